// Round 1
// baseline (40493.695 us; speedup 1.0000x reference)
//
#include <hip/hip_runtime.h>

#define LSEQ 8128
#define NB 8
#define CORR_CAP 8192
#define HST 264          // hT row stride (shorts); 528 B spreads banks
#define HROWS 9          // 8 batch rows + 1 shared zero row (lm>=8 broadcast)
#define HT1 (HROWS * HST)
#define RINGSZ 512
#define FLAG_R0 0
#define FLAG_H0 32
#define FLAG_H1 64
#define PROG_R1 96

typedef __attribute__((ext_vector_type(8))) short short8;
typedef __attribute__((ext_vector_type(4))) float float4e;

#define MFMA16(a, b, c) __builtin_amdgcn_mfma_f32_16x16x32_bf16((a), (b), (c), 0, 0, 0)

// ---- workspace layout (bytes) ----
#define WS_P      4096ul
#define WS_AEE    528384ul
#define WS_VPN    536576ul      // bf16 [8128][1024]
#define WS_EIDX   17182720ul
#define WS_CORR   17444864ul    // bf16 [8192][1024]
#define WS_URING  34222080ul    // bf16 ring [512][8][1024]
#define WS_H0     42610688ul    // bf16 [8129][8][256]
#define WS_H1     75907072ul

static __device__ __forceinline__ unsigned short f2bf(float f) {
  unsigned u = __float_as_uint(f);
  return (unsigned short)((u + 0x7fffu + ((u >> 16) & 1u)) >> 16);  // RNE
}
static __device__ __forceinline__ float blo(unsigned u) { return __uint_as_float(u << 16); }
static __device__ __forceinline__ float bhi(unsigned u) { return __uint_as_float(u & 0xffff0000u); }
static __device__ __forceinline__ unsigned addbf2(unsigned a, unsigned b) {
  float lo = blo(a) + blo(b), hi = bhi(a) + bhi(b);
  return (unsigned)f2bf(lo) | ((unsigned)f2bf(hi) << 16);
}
static __device__ __forceinline__ short8 pack8f(const float* __restrict__ p) {
  short8 r;
#pragma unroll
  for (int i = 0; i < 8; ++i) r[i] = (short)f2bf(p[i]);
  return r;
}
static __device__ __forceinline__ unsigned aload(const unsigned* p) {
  return __hip_atomic_load(p, __ATOMIC_RELAXED, __HIP_MEMORY_SCOPE_AGENT);
}
static __device__ __forceinline__ void astore(unsigned* p, unsigned v) {
  __hip_atomic_store(p, v, __ATOMIC_RELAXED, __HIP_MEMORY_SCOPE_AGENT);
}
static __device__ __forceinline__ unsigned long long aload64(const unsigned long long* p) {
  return __hip_atomic_load(p, __ATOMIC_RELAXED, __HIP_MEMORY_SCOPE_AGENT);
}
static __device__ __forceinline__ void astore64(unsigned long long* p, unsigned long long v) {
  __hip_atomic_store(p, v, __ATOMIC_RELAXED, __HIP_MEMORY_SCOPE_AGENT);
}
static __device__ __forceinline__ void fencev() {
  asm volatile("s_waitcnt vmcnt(0)" ::: "memory");
}
static __device__ __forceinline__ void cbar() { asm volatile("" ::: "memory"); }
static __device__ __forceinline__ void barrier_lgkm() {
  asm volatile("s_waitcnt lgkmcnt(0)\ns_barrier" ::: "memory");
}
static __device__ __forceinline__ float sigf(float x) { return 1.f / (1.f + __expf(-x)); }
static __device__ __forceinline__ float tanhf2(float x) { return 2.f / (1.f + __expf(-2.f * x)) - 1.f; }

// ---- preps (unchanged) ----
__global__ void k_prep_P(const float* __restrict__ Wih0, const float* __restrict__ ewW2,
                         float* __restrict__ P) {
  int idx = blockIdx.x * 256 + threadIdx.x;
  int g = idx >> 7, k = idx & 127;
  const float* wr = Wih0 + (size_t)g * 320 + 128;
  float s = 0.f;
#pragma unroll 8
  for (int j = 0; j < 64; ++j) s += wr[j] * ewW2[j * 128 + k];
  P[idx] = s;
}

__global__ void k_prep_aee_init(const float* __restrict__ Wih0, const float* __restrict__ ee,
                                const float* __restrict__ b1, const float* __restrict__ b2,
                                const float* __restrict__ P, const float* __restrict__ inith,
                                float* __restrict__ aee, unsigned short* __restrict__ h0u,
                                unsigned short* __restrict__ h1u) {
  int idx = blockIdx.x * 256 + threadIdx.x;  // < 2048
  int s = idx >> 10, g = idx & 1023;
  const float* wr = Wih0 + (size_t)g * 320;
  float a = 0.f;
#pragma unroll 8
  for (int i = 0; i < 128; ++i) a += wr[i] * ee[s * 128 + i];
#pragma unroll 8
  for (int j = 0; j < 64; ++j) a += wr[128 + j] * b2[j];
  const float* pr = P + (size_t)g * 128;
#pragma unroll 8
  for (int k = 0; k < 128; ++k) a += pr[k] * fmaxf(b1[k], 0.f);
  aee[s * 1024 + g] = a;
  unsigned short hv = f2bf(inith[idx & 127]);
  h0u[idx] = hv;
  h1u[idx] = hv;
}

__global__ void k_prep_vpn(const float* __restrict__ Wih0, const float* __restrict__ nemb,
                           const float* __restrict__ aee, unsigned short* __restrict__ vpn) {
  __shared__ float pn[128];
  int t = blockIdx.x, tid = threadIdx.x;
  if (tid < 32) {
    float div = expf(-9.2103403719761836f * (float)(2 * tid) / 64.f);
    float ang = (float)t * div;
    pn[2 * tid] = sinf(ang);
    pn[2 * tid + 1] = cosf(ang);
  } else if (tid < 96) {
    int r = (int)((1.f + sqrtf(8.f * (float)t + 1.f)) * 0.5f);
    while (r * (r + 1) / 2 <= t) ++r;
    while (r * (r - 1) / 2 > t) --r;
    pn[64 + (tid - 32)] = nemb[r * 64 + (tid - 32)];
  }
  __syncthreads();
#pragma unroll
  for (int rr = 0; rr < 4; ++rr) {
    int row = rr * 256 + tid;
    const float* wr = Wih0 + (size_t)row * 320 + 192;
    float s = 0.f;
#pragma unroll 8
    for (int i = 0; i < 128; ++i) s += wr[i] * pn[i];
    vpn[(size_t)t * 1024 + row] = f2bf(s + aee[row]);
  }
}

__global__ void k_prep_eidx(const float* __restrict__ xadj, int* __restrict__ eidx,
                            unsigned* __restrict__ counter) {
  int idx = blockIdx.x * 256 + threadIdx.x;
  if (idx >= NB * LSEQ) return;
  int t = idx % LSEQ;
  int e = -1;
  if (t > 0 && xadj[idx - 1] > 0.f) {
    e = (int)atomicAdd(counter, 1u);
    if (e >= CORR_CAP) e = -1;
  }
  eidx[idx] = e;
}

__global__ void k_prep_corr(const float* __restrict__ xadj, const float* __restrict__ w1,
                            const float* __restrict__ b1, const float* __restrict__ P,
                            const float* __restrict__ aee, const int* __restrict__ eidx,
                            unsigned short* __restrict__ corr) {
  __shared__ float rh[128];
  int bid = blockIdx.x;
  int e = eidx[bid];
  if (e < 0) return;
  int tid = threadIdx.x;
  float wt = xadj[bid - 1];
  if (tid < 128) {
    float bb = b1[tid];
    rh[tid] = fmaxf(wt * w1[tid] + bb, 0.f) - fmaxf(bb, 0.f);
  }
  __syncthreads();
#pragma unroll
  for (int rr = 0; rr < 4; ++rr) {
    int row = rr * 256 + tid;
    const float* pr = P + (size_t)row * 128;
    float s = 0.f;
#pragma unroll 8
    for (int k = 0; k < 128; ++k) s += pr[k] * rh[k];
    corr[(size_t)e * 1024 + row] = f2bf(s + aee[1024 + row] - aee[row]);
  }
}

// ============ persistent single-CU recurrence LSTM ============
// W rows permuted at load time: tile tt = (gate g = tt>>1, pair p = tt&1),
// rows g*256 + wv*32 + p*16 + lm. So each wave owns ALL 4 gates of its
// 32-wide j-slice -> MFMA accs stay in the owning lane; update is
// in-register (c in VGPRs), ONE barrier/step, no gbuf/cbuf LDS round-trip.
template <int LAYER>
static __device__ __forceinline__ void recur(
    const float* __restrict__ Wrec, const unsigned short* __restrict__ vpn,
    const int* __restrict__ eidx, const unsigned short* __restrict__ corr,
    const unsigned* __restrict__ uring, const float* __restrict__ inith,
    const float* __restrict__ initc, unsigned* flags, unsigned* hout,
    short* wlds, unsigned short* hT, int tid) {
  const int wv = tid >> 6, l = tid & 63, lm = l & 15, lk = l >> 4;
  const int lmr = (lm < 8) ? lm : 8;   // lanes 8-15 broadcast the zero row (B operand)
  const int bb = lm & 7;               // owned batch
  const int pp = lm >> 3;              // owned pair (0: j-slice, 1: +16)
  const int jj = wv * 32 + pp * 16 + lk * 4;  // owned j (4 values jj..jj+3)
  unsigned budget = 20000000u;

  // zero both hT buffers (incl. zero row 8 and padding)
  for (int i = tid; i < 2 * HT1; i += 512) hT[i] = 0;
  __syncthreads();
  // initial h -> buffer 1 (step 0 reads buf[(t-1)&1] = buf 1)
  {
    unsigned h01 = (unsigned)f2bf(inith[jj & 127]) | ((unsigned)f2bf(inith[(jj + 1) & 127]) << 16);
    unsigned h23 = (unsigned)f2bf(inith[(jj + 2) & 127]) | ((unsigned)f2bf(inith[(jj + 3) & 127]) << 16);
    *(uint2*)&hT[HT1 + bb * HST + jj] = make_uint2(h01, h23);
  }
  float cc[4];
#pragma unroll
  for (int r = 0; r < 4; ++r) cc[r] = initc[(jj + r) & 127];

  // weights: 8 m-tiles/wave (gate-major); tiles 0-5 in regs, 6-7 (o-gate) in LDS
  short8 wf[6][8];
#pragma unroll
  for (int tt = 0; tt < 6; ++tt) {
    int row = (tt >> 1) * 256 + wv * 32 + (tt & 1) * 16 + lm;
#pragma unroll
    for (int ks = 0; ks < 8; ++ks)
      wf[tt][ks] = pack8f(Wrec + (size_t)row * 256 + ks * 32 + lk * 8);
  }
#pragma unroll
  for (int tt = 6; tt < 8; ++tt) {
    int row = 3 * 256 + wv * 32 + (tt & 1) * 16 + lm;
    int s = wv * 2 + (tt - 6);
#pragma unroll
    for (int ks = 0; ks < 8; ++ks) {
      short8 w = pack8f(Wrec + (size_t)row * 256 + ks * 32 + lk * 8);
      *(short8*)&wlds[((s * 8 + ks) * 64 + l) * 8] = w;
    }
  }
  __syncthreads();

  int e_nxt = 0;
  if (LAYER == 0) e_nxt = eidx[bb * LSEQ];  // e for t=0 (always -1)
  unsigned Tc0 = 0, Tc1 = 0;

  for (int t = 0; t < LSEQ; ++t) {
    const int rd = ((t + 1) & 1) * HT1;  // h(t-1) buffer
    const int wr = (t & 1) * HT1;        // h(t) buffer
    // ---- per-lane input gates: vv[g] = 4 bf16 at (bb, gate g, jj..jj+3) ----
    uint2 vv[4];
    if (LAYER == 0) {
      const uint2* vp = (const uint2*)(vpn + (size_t)t * 1024);
      const int j4 = jj >> 2;
#pragma unroll
      for (int g = 0; g < 4; ++g) vv[g] = vp[g * 64 + j4];
      int e = e_nxt;
      if (t + 1 < LSEQ) e_nxt = eidx[bb * LSEQ + t + 1];  // prefetch next
      if (e >= 0) {
        const uint2* cp = (const uint2*)(corr + (size_t)e * 1024);
#pragma unroll
        for (int g = 0; g < 4; ++g) {
          uint2 cv = cp[g * 64 + j4];
          vv[g].x = addbf2(vv[g].x, cv.x);
          vv[g].y = addbf2(vv[g].y, cv.y);
        }
      }
    } else {
      unsigned Tm = (Tc0 < Tc1) ? Tc0 : Tc1;
      while (Tm < (unsigned)(t + 1)) {
        Tc0 = aload(flags + FLAG_H0);
        Tc1 = aload(flags + FLAG_H1);
        Tm = (Tc0 < Tc1) ? Tc0 : Tc1;
        if (--budget == 0) break;
        asm volatile("s_sleep 1");
      }
      cbar();
      const unsigned long long* ub =
          (const unsigned long long*)(uring + (size_t)(t & (RINGSZ - 1)) * 4096 + bb * 512);
      const int j2q = jj >> 3;  // 64-bit index within gate block (128 dwords = 64 quads)
#pragma unroll
      for (int g = 0; g < 4; ++g) {
        unsigned long long q = aload64(ub + g * 64 + j2q);
        vv[g].x = (unsigned)q;
        vv[g].y = (unsigned)(q >> 32);
      }
    }

    // ---- MFMA phase: ks-major, 8 independent acc chains ----
    float4e acc[8];
#pragma unroll
    for (int tt = 0; tt < 8; ++tt) acc[tt] = (float4e){0.f, 0.f, 0.f, 0.f};
    __builtin_amdgcn_s_setprio(1);
#pragma unroll
    for (int ks = 0; ks < 8; ++ks) {
      short8 hb = *(const short8*)(hT + rd + lmr * HST + ks * 32 + lk * 8);
      short8 w6 = *(const short8*)&wlds[(((wv * 2 + 0) * 8 + ks) * 64 + l) * 8];
      short8 w7 = *(const short8*)&wlds[(((wv * 2 + 1) * 8 + ks) * 64 + l) * 8];
#pragma unroll
      for (int tt = 0; tt < 6; ++tt) acc[tt] = MFMA16(wf[tt][ks], hb, acc[tt]);
      acc[6] = MFMA16(w6, hb, acc[6]);
      acc[7] = MFMA16(w7, hb, acc[7]);
    }
    __builtin_amdgcn_s_setprio(0);

    // ---- gather gates into owning lane: pair-1 accs shuffle to lanes lm>=8 ----
    float gt[4][4];
#pragma unroll
    for (int g = 0; g < 4; ++g) {
      float4e aP0 = acc[(g < 3) ? 2 * g : 6];
      float4e aP1 = acc[(g < 3) ? 2 * g + 1 : 7];
      float vf0 = blo(vv[g].x), vf1 = bhi(vv[g].x);
      float vf2 = blo(vv[g].y), vf3 = bhi(vv[g].y);
#pragma unroll
      for (int r = 0; r < 4; ++r) {
        float sh = __shfl_xor(aP1[r], 8);
        float base = (lm < 8) ? aP0[r] : sh;
        float vf = (r == 0) ? vf0 : (r == 1) ? vf1 : (r == 2) ? vf2 : vf3;
        gt[g][r] = base + vf;
      }
    }
    // ---- in-register LSTM update: lane owns (bb, jj..jj+3), c in VGPRs ----
    float hv[4];
#pragma unroll
    for (int r = 0; r < 4; ++r) {
      float cn = sigf(gt[1][r]) * cc[r] + sigf(gt[0][r]) * tanhf2(gt[2][r]);
      cc[r] = cn;
      hv[r] = sigf(gt[3][r]) * tanhf2(cn);
    }
    unsigned h01 = (unsigned)f2bf(hv[0]) | ((unsigned)f2bf(hv[1]) << 16);
    unsigned h23 = (unsigned)f2bf(hv[2]) | ((unsigned)f2bf(hv[3]) << 16);
    *(uint2*)&hT[wr + bb * HST + jj] = make_uint2(h01, h23);
    astore64((unsigned long long*)(hout + (size_t)(t + 1) * 1024 + bb * 128 + (jj >> 1)),
             (unsigned long long)h01 | ((unsigned long long)h23 << 32));

    // ---- single barrier/step; flag publish every 8 (L0) / 64 (L1) ----
    if (LAYER == 0) {
      if ((t & 7) == 7) fencev();
      barrier_lgkm();
      if ((t & 7) == 7 && tid == 0) astore(flags + FLAG_R0, (unsigned)(t + 1));
    } else {
      barrier_lgkm();
      if ((t & 63) == 63 && tid == 0) astore(flags + PROG_R1, (unsigned)(t + 1));
    }
  }
}

// uprod: barrier-free in steady state. B-fragments read per-lane straight
// from global h0w (no hB staging); waves sync only at the every-8 publish.
static __device__ __forceinline__ void uprod(
    int hid, const float* __restrict__ Wih1, unsigned* flags,
    const unsigned* __restrict__ h0w, unsigned* uring, int tid) {
  const int wv = tid >> 6, l = tid & 63, lm = l & 15, lk = l >> 4;
  unsigned budget = 20000000u;
  short8 wf[4][8];
#pragma unroll
  for (int tt = 0; tt < 4; ++tt) {
    int row = hid * 512 + (wv * 4 + tt) * 16 + lm;
#pragma unroll
    for (int ks = 0; ks < 8; ++ks)
      wf[tt][ks] = pack8f(Wih1 + (size_t)row * 256 + ks * 32 + lk * 8);
  }
  unsigned Fc = 0, Pc = 0;
  for (int t = 0; t < LSEQ; ++t) {
    while (Fc < (unsigned)(t + 1)) {  // h0 slot t+1 published?
      Fc = aload(flags + FLAG_R0);
      if (--budget == 0) break;
      asm volatile("s_sleep 1");
    }
    while ((unsigned)t >= Pc + 448u) {  // ring back-pressure
      Pc = aload(flags + PROG_R1);
      if (--budget == 0) break;
      asm volatile("s_sleep 1");
    }
    cbar();
    short8 hb8[8];
#pragma unroll
    for (int ks = 0; ks < 8; ++ks) {
      short8 hb = {};
      if (lm < 8)
        hb = *(const short8*)(h0w + (size_t)(t + 1) * 1024 + lm * 128 + ks * 16 + lk * 4);
      hb8[ks] = hb;
    }
    float4e a[4];
#pragma unroll
    for (int tt = 0; tt < 4; ++tt) a[tt] = (float4e){0.f, 0.f, 0.f, 0.f};
#pragma unroll
    for (int ks = 0; ks < 8; ++ks) {
#pragma unroll
      for (int tt = 0; tt < 4; ++tt) a[tt] = MFMA16(wf[tt][ks], hb8[ks], a[tt]);
    }
    int slot = t & (RINGSZ - 1);
    if (lm < 8) {
#pragma unroll
      for (int tt = 0; tt < 4; ++tt) {
        int g0 = hid * 512 + (wv * 4 + tt) * 16 + lk * 4;
        unsigned p0 = (unsigned)f2bf(a[tt][0]) | ((unsigned)f2bf(a[tt][1]) << 16);
        unsigned p1 = (unsigned)f2bf(a[tt][2]) | ((unsigned)f2bf(a[tt][3]) << 16);
        unsigned* up = uring + (size_t)slot * 4096 + lm * 512 + (g0 >> 1);
        astore(up, p0);
        astore(up + 1, p1);
      }
    }
    if ((t & 7) == 7) {
      fencev();
      __syncthreads();
      if (tid == 0) astore(flags + (hid ? FLAG_H1 : FLAG_H0), (unsigned)(t + 1));
    }
  }
}

__global__ __launch_bounds__(512, 1) void k_lstm(
    const float* __restrict__ Whh0, const float* __restrict__ Wih1,
    const float* __restrict__ Whh1, const unsigned short* __restrict__ vpn,
    const int* __restrict__ eidx, const unsigned short* __restrict__ corr,
    const float* __restrict__ inith, const float* __restrict__ initc,
    unsigned* flags, unsigned* uring, unsigned* h0w, unsigned* h1w) {
  __shared__ __align__(16) short wlds[16 * 8 * 64 * 8];       // 131072 B
  __shared__ __align__(16) unsigned short hT[2 * HT1];        // 9504 B -> 140576 total
  const int tid = threadIdx.x;
  const int bx = blockIdx.x;
  if (bx == 0)
    recur<0>(Whh0, vpn, eidx, corr, nullptr, inith, initc, flags, h0w, wlds, hT, tid);
  else if (bx == 1)
    recur<1>(Whh1, nullptr, nullptr, nullptr, uring, inith, initc, flags, h1w, wlds, hT, tid);
  else
    uprod(bx - 2, Wih1, flags, h0w, uring, tid);
}

// ---- heads (unchanged) ----
__global__ __launch_bounds__(256, 2) void k_heads(
    const unsigned short* __restrict__ h1u, const float* __restrict__ xadj,
    const float* __restrict__ lgW1, const float* __restrict__ lgb1,
    const float* __restrict__ lgW2, const float* __restrict__ lgb2,
    const float* __restrict__ muW1, const float* __restrict__ mub1,
    const float* __restrict__ muW2, const float* __restrict__ mub2,
    const float* __restrict__ vaW1, const float* __restrict__ vab1,
    const float* __restrict__ vaW2, const float* __restrict__ vab2,
    float* dout) {
  __shared__ float vals[4][3][64];
  const int tid = threadIdx.x;
  const int v = tid >> 6, l = tid & 63, lm = l & 15, lk = l >> 4;
  const int wid = blockIdx.x * 4 + v;
  const int m0 = wid * 64;

  short8 afr[4][8];
#pragma unroll
  for (int tt = 0; tt < 4; ++tt)
#pragma unroll
    for (int ks = 0; ks < 8; ++ks)
      afr[tt][ks] = *(const short8*)(h1u + (size_t)(m0 + tt * 16 + lm) * 256 + 2048 + ks * 32 + lk * 8);

  const float* W1s[3] = {lgW1, muW1, vaW1};
  const float* b1s[3] = {lgb1, mub1, vab1};
  const float* W2s[3] = {lgW2, muW2, vaW2};

  for (int h = 0; h < 3; ++h) {
    float accr[4][4];
#pragma unroll
    for (int tt = 0; tt < 4; ++tt)
#pragma unroll
      for (int r = 0; r < 4; ++r) accr[tt][r] = 0.f;
    const float* W1p = W1s[h];
    const float* b1p = b1s[h];
    const float* W2p = W2s[h];
    for (int nt = 0; nt < 32; ++nt) {
      float4e c0 = {0.f, 0.f, 0.f, 0.f}, c1 = c0, c2 = c0, c3 = c0;
      const float* wp = W1p + (size_t)(nt * 16 + lm) * 256;
#pragma unroll
      for (int ks = 0; ks < 8; ++ks) {
        short8 bfr = pack8f(wp + ks * 32 + lk * 8);
        c0 = MFMA16(afr[0][ks], bfr, c0);
        c1 = MFMA16(afr[1][ks], bfr, c1);
        c2 = MFMA16(afr[2][ks], bfr, c2);
        c3 = MFMA16(afr[3][ks], bfr, c3);
      }
      float bias = b1p[nt * 16 + lm], w2v = W2p[nt * 16 + lm];
#pragma unroll
      for (int r = 0; r < 4; ++r) {
        accr[0][r] += fmaxf(c0[r] + bias, 0.f) * w2v;
        accr[1][r] += fmaxf(c1[r] + bias, 0.f) * w2v;
        accr[2][r] += fmaxf(c2[r] + bias, 0.f) * w2v;
        accr[3][r] += fmaxf(c3[r] + bias, 0.f) * w2v;
      }
    }
#pragma unroll
    for (int tt = 0; tt < 4; ++tt)
#pragma unroll
      for (int r = 0; r < 4; ++r) {
        float a2 = accr[tt][r];
        a2 += __shfl_xor(a2, 1);
        a2 += __shfl_xor(a2, 2);
        a2 += __shfl_xor(a2, 4);
        a2 += __shfl_xor(a2, 8);
        if (lm == 0) vals[v][h][tt * 16 + lk * 4 + r] = a2;
      }
  }
  __syncthreads();
  {
    int m = m0 + l;
    int tq = m >> 3, b = m & 7;
    float z = vals[v][0][l] + lgb2[0];
    float mu = vals[v][1][l] + mub2[0];
    float lv = vals[v][2][l] + vab2[0];
    float x = xadj[(size_t)b * LSEQ + tq];
    float xt = (x > 0.f) ? 1.f : 0.f;
    float lr = fmaxf(z, 0.f) - z * xt + log1pf(expf(-fabsf(z)));
    float lw = 0.f;
    if (x > 0.f) {
      float sm = (x > 20.f) ? x : logf(expm1f(fminf(x, 20.f)));
      float d = mu - sm;
      lw = 0.5f * (lv + d * d * expf(-lv));
    }
#pragma unroll
    for (int d2 = 1; d2 < 64; d2 <<= 1) {
      lr += __shfl_xor(lr, d2);
      lw += __shfl_xor(lw, d2);
    }
    if (l == 0) {
      atomicAdd(dout + 0, lr * (1.f / 1024.f));
      atomicAdd(dout + 1, lw * (1.f / 1024.f));
    }
  }
}

extern "C" void kernel_launch(void* const* d_in, const int* in_sizes, int n_in,
                              void* d_out, int out_size, void* d_ws, size_t ws_size,
                              hipStream_t stream) {
  const float* x_adj = (const float*)d_in[0];
  const float* ee    = (const float*)d_in[1];
  const float* nemb  = (const float*)d_in[2];
  const float* ewW1  = (const float*)d_in[3];
  const float* ewb1  = (const float*)d_in[4];
  const float* ewW2  = (const float*)d_in[5];
  const float* ewb2  = (const float*)d_in[6];
  const float* Wih0  = (const float*)d_in[7];
  const float* Whh0  = (const float*)d_in[8];
  const float* Wih1  = (const float*)d_in[9];
  const float* Whh1  = (const float*)d_in[10];
  const float* muW1  = (const float*)d_in[11];
  const float* mub1  = (const float*)d_in[12];
  const float* muW2  = (const float*)d_in[13];
  const float* mub2  = (const float*)d_in[14];
  const float* vaW1  = (const float*)d_in[15];
  const float* vab1  = (const float*)d_in[16];
  const float* vaW2  = (const float*)d_in[17];
  const float* vab2  = (const float*)d_in[18];
  const float* lgW1  = (const float*)d_in[19];
  const float* lgb1  = (const float*)d_in[20];
  const float* lgW2  = (const float*)d_in[21];
  const float* lgb2  = (const float*)d_in[22];
  const float* inith = (const float*)d_in[23];
  const float* initc = (const float*)d_in[24];

  char* wsb = (char*)d_ws;
  unsigned* flags      = (unsigned*)wsb;
  unsigned* counter    = (unsigned*)(wsb + 512);
  float* P             = (float*)(wsb + WS_P);
  float* aee           = (float*)(wsb + WS_AEE);
  unsigned short* vpn  = (unsigned short*)(wsb + WS_VPN);
  int* eidx            = (int*)(wsb + WS_EIDX);
  unsigned short* corr = (unsigned short*)(wsb + WS_CORR);
  unsigned* uring      = (unsigned*)(wsb + WS_URING);
  unsigned* h0w        = (unsigned*)(wsb + WS_H0);
  unsigned* h1w        = (unsigned*)(wsb + WS_H1);
  unsigned short* h0u  = (unsigned short*)(wsb + WS_H0);
  unsigned short* h1u  = (unsigned short*)(wsb + WS_H1);

  (void)in_sizes; (void)n_in; (void)ws_size;

  hipMemsetAsync(d_ws, 0, 4096, stream);
  hipMemsetAsync(d_out, 0, (size_t)out_size * 4, stream);

  k_prep_P<<<512, 256, 0, stream>>>(Wih0, ewW2, P);
  k_prep_aee_init<<<8, 256, 0, stream>>>(Wih0, ee, ewb1, ewb2, P, inith, aee, h0u, h1u);
  k_prep_vpn<<<LSEQ, 256, 0, stream>>>(Wih0, nemb, aee, vpn);
  k_prep_eidx<<<(NB * LSEQ) / 256, 256, 0, stream>>>(x_adj, eidx, counter);
  k_prep_corr<<<NB * LSEQ, 256, 0, stream>>>(x_adj, ewW1, ewb1, P, aee, eidx, corr);
  k_lstm<<<4, 512, 0, stream>>>(Whh0, Wih1, Whh1, vpn, eidx, corr, inith, initc,
                                flags, uring, h0w, h1w);
  k_heads<<<254, 256, 0, stream>>>(h1u, x_adj, lgW1, lgb1, lgW2, lgb2,
                                   muW1, mub1, muW2, mub2, vaW1, vab1, vaW2, vab2,
                                   (float*)d_out);
}

// Round 2
// 39209.103 us; speedup vs baseline: 1.0328x; 1.0328x over previous
//
#include <hip/hip_runtime.h>

#define LSEQ 8128
#define NB 8
#define CORR_CAP 8192
#define HST 264          // hT row stride (shorts); 528 B spreads banks
#define HROWS 9          // 8 batch rows + 1 shared zero row (lm>=8 broadcast)
#define HT1 (HROWS * HST)
#define RINGSZ 512
#define FLAG_R0 0
#define FLAG_H0 32
#define FLAG_H1 64
#define PROG_R1 96

typedef __attribute__((ext_vector_type(8))) short short8;
typedef __attribute__((ext_vector_type(4))) float float4e;

#define MFMA16(a, b, c) __builtin_amdgcn_mfma_f32_16x16x32_bf16((a), (b), (c), 0, 0, 0)

// ---- workspace layout (bytes) ----
#define WS_P      4096ul
#define WS_AEE    528384ul
#define WS_VPN    536576ul      // bf16 [8128][1024]
#define WS_EIDX   17182720ul
#define WS_CORR   17444864ul    // bf16 [8192][1024]
#define WS_URING  34222080ul    // bf16 ring [512][8][1024]
#define WS_H0     42610688ul    // bf16 [8129][8][256]
#define WS_H1     75907072ul

static __device__ __forceinline__ unsigned short f2bf(float f) {
  unsigned u = __float_as_uint(f);
  return (unsigned short)((u + 0x7fffu + ((u >> 16) & 1u)) >> 16);  // RNE
}
static __device__ __forceinline__ float blo(unsigned u) { return __uint_as_float(u << 16); }
static __device__ __forceinline__ float bhi(unsigned u) { return __uint_as_float(u & 0xffff0000u); }
static __device__ __forceinline__ unsigned addbf2(unsigned a, unsigned b) {
  float lo = blo(a) + blo(b), hi = bhi(a) + bhi(b);
  return (unsigned)f2bf(lo) | ((unsigned)f2bf(hi) << 16);
}
static __device__ __forceinline__ short8 pack8f(const float* __restrict__ p) {
  short8 r;
#pragma unroll
  for (int i = 0; i < 8; ++i) r[i] = (short)f2bf(p[i]);
  return r;
}
static __device__ __forceinline__ unsigned aload(const unsigned* p) {
  return __hip_atomic_load(p, __ATOMIC_RELAXED, __HIP_MEMORY_SCOPE_AGENT);
}
static __device__ __forceinline__ void astore(unsigned* p, unsigned v) {
  __hip_atomic_store(p, v, __ATOMIC_RELAXED, __HIP_MEMORY_SCOPE_AGENT);
}
static __device__ __forceinline__ unsigned long long aload64(const unsigned long long* p) {
  return __hip_atomic_load(p, __ATOMIC_RELAXED, __HIP_MEMORY_SCOPE_AGENT);
}
static __device__ __forceinline__ void astore64(unsigned long long* p, unsigned long long v) {
  __hip_atomic_store(p, v, __ATOMIC_RELAXED, __HIP_MEMORY_SCOPE_AGENT);
}
static __device__ __forceinline__ void fencev() {
  asm volatile("s_waitcnt vmcnt(0)" ::: "memory");
}
static __device__ __forceinline__ void cbar() { asm volatile("" ::: "memory"); }
static __device__ __forceinline__ void barrier_lgkm() {
  asm volatile("s_waitcnt lgkmcnt(0)\ns_barrier" ::: "memory");
}
static __device__ __forceinline__ float sigf(float x) { return 1.f / (1.f + __expf(-x)); }
static __device__ __forceinline__ float tanhf2(float x) { return 2.f / (1.f + __expf(-2.f * x)) - 1.f; }

// ---- preps (unchanged) ----
__global__ void k_prep_P(const float* __restrict__ Wih0, const float* __restrict__ ewW2,
                         float* __restrict__ P) {
  int idx = blockIdx.x * 256 + threadIdx.x;
  int g = idx >> 7, k = idx & 127;
  const float* wr = Wih0 + (size_t)g * 320 + 128;
  float s = 0.f;
#pragma unroll 8
  for (int j = 0; j < 64; ++j) s += wr[j] * ewW2[j * 128 + k];
  P[idx] = s;
}

__global__ void k_prep_aee_init(const float* __restrict__ Wih0, const float* __restrict__ ee,
                                const float* __restrict__ b1, const float* __restrict__ b2,
                                const float* __restrict__ P, const float* __restrict__ inith,
                                float* __restrict__ aee, unsigned short* __restrict__ h0u,
                                unsigned short* __restrict__ h1u) {
  int idx = blockIdx.x * 256 + threadIdx.x;  // < 2048
  int s = idx >> 10, g = idx & 1023;
  const float* wr = Wih0 + (size_t)g * 320;
  float a = 0.f;
#pragma unroll 8
  for (int i = 0; i < 128; ++i) a += wr[i] * ee[s * 128 + i];
#pragma unroll 8
  for (int j = 0; j < 64; ++j) a += wr[128 + j] * b2[j];
  const float* pr = P + (size_t)g * 128;
#pragma unroll 8
  for (int k = 0; k < 128; ++k) a += pr[k] * fmaxf(b1[k], 0.f);
  aee[s * 1024 + g] = a;
  unsigned short hv = f2bf(inith[idx & 127]);
  h0u[idx] = hv;
  h1u[idx] = hv;
}

__global__ void k_prep_vpn(const float* __restrict__ Wih0, const float* __restrict__ nemb,
                           const float* __restrict__ aee, unsigned short* __restrict__ vpn) {
  __shared__ float pn[128];
  int t = blockIdx.x, tid = threadIdx.x;
  if (tid < 32) {
    float div = expf(-9.2103403719761836f * (float)(2 * tid) / 64.f);
    float ang = (float)t * div;
    pn[2 * tid] = sinf(ang);
    pn[2 * tid + 1] = cosf(ang);
  } else if (tid < 96) {
    int r = (int)((1.f + sqrtf(8.f * (float)t + 1.f)) * 0.5f);
    while (r * (r + 1) / 2 <= t) ++r;
    while (r * (r - 1) / 2 > t) --r;
    pn[64 + (tid - 32)] = nemb[r * 64 + (tid - 32)];
  }
  __syncthreads();
#pragma unroll
  for (int rr = 0; rr < 4; ++rr) {
    int row = rr * 256 + tid;
    const float* wr = Wih0 + (size_t)row * 320 + 192;
    float s = 0.f;
#pragma unroll 8
    for (int i = 0; i < 128; ++i) s += wr[i] * pn[i];
    vpn[(size_t)t * 1024 + row] = f2bf(s + aee[row]);
  }
}

__global__ void k_prep_eidx(const float* __restrict__ xadj, int* __restrict__ eidx,
                            unsigned* __restrict__ counter) {
  int idx = blockIdx.x * 256 + threadIdx.x;
  if (idx >= NB * LSEQ) return;
  int t = idx % LSEQ;
  int e = -1;
  if (t > 0 && xadj[idx - 1] > 0.f) {
    e = (int)atomicAdd(counter, 1u);
    if (e >= CORR_CAP) e = -1;
  }
  eidx[idx] = e;
}

__global__ void k_prep_corr(const float* __restrict__ xadj, const float* __restrict__ w1,
                            const float* __restrict__ b1, const float* __restrict__ P,
                            const float* __restrict__ aee, const int* __restrict__ eidx,
                            unsigned short* __restrict__ corr) {
  __shared__ float rh[128];
  int bid = blockIdx.x;
  int e = eidx[bid];
  if (e < 0) return;
  int tid = threadIdx.x;
  float wt = xadj[bid - 1];
  if (tid < 128) {
    float bb = b1[tid];
    rh[tid] = fmaxf(wt * w1[tid] + bb, 0.f) - fmaxf(bb, 0.f);
  }
  __syncthreads();
#pragma unroll
  for (int rr = 0; rr < 4; ++rr) {
    int row = rr * 256 + tid;
    const float* pr = P + (size_t)row * 128;
    float s = 0.f;
#pragma unroll 8
    for (int k = 0; k < 128; ++k) s += pr[k] * rh[k];
    corr[(size_t)e * 1024 + row] = f2bf(s + aee[1024 + row] - aee[row]);
  }
}

// ============ persistent single-CU recurrence LSTM ============
// W rows permuted at load time: tile tt = (gate g = tt>>1, pair p = tt&1),
// rows g*256 + wv*32 + p*16 + lm. Each wave owns ALL 4 gates of its
// 32-wide j-slice -> MFMA accs stay in the owning lane; update is
// in-register (c in VGPRs), ONE barrier/step, no gbuf/cbuf LDS round-trip.
template <int LAYER>
static __device__ __forceinline__ void recur(
    const float* __restrict__ Wrec, const unsigned short* __restrict__ vpn,
    const int* __restrict__ eidx, const unsigned short* __restrict__ corr,
    const unsigned* __restrict__ uring, const float* __restrict__ inith,
    const float* __restrict__ initc, unsigned* flags, unsigned* hout,
    short* wlds, unsigned short* hT, int tid) {
  const int wv = tid >> 6, l = tid & 63, lm = l & 15, lk = l >> 4;
  const int lmr = (lm < 8) ? lm : 8;   // lanes 8-15 broadcast the zero row (B operand)
  const int bb = lm & 7;               // owned batch
  const int pp = lm >> 3;              // owned pair (0: j-slice, 1: +16)
  const int jj = wv * 32 + pp * 16 + lk * 4;  // owned j (4 values jj..jj+3)
  unsigned budget = 20000000u;

  // zero both hT buffers (incl. zero row 8 and padding)
  for (int i = tid; i < 2 * HT1; i += 512) hT[i] = 0;
  __syncthreads();
  // initial h -> buffer 1 (step 0 reads buf[(t-1)&1] = buf 1)
  {
    unsigned h01 = (unsigned)f2bf(inith[jj & 127]) | ((unsigned)f2bf(inith[(jj + 1) & 127]) << 16);
    unsigned h23 = (unsigned)f2bf(inith[(jj + 2) & 127]) | ((unsigned)f2bf(inith[(jj + 3) & 127]) << 16);
    *(uint2*)&hT[HT1 + bb * HST + jj] = make_uint2(h01, h23);
  }
  float cc[4];
#pragma unroll
  for (int r = 0; r < 4; ++r) cc[r] = initc[(jj + r) & 127];

  // weights: 8 m-tiles/wave (gate-major); tiles 0-5 in regs, 6-7 (o-gate) in LDS
  short8 wf[6][8];
#pragma unroll
  for (int tt = 0; tt < 6; ++tt) {
    int row = (tt >> 1) * 256 + wv * 32 + (tt & 1) * 16 + lm;
#pragma unroll
    for (int ks = 0; ks < 8; ++ks)
      wf[tt][ks] = pack8f(Wrec + (size_t)row * 256 + ks * 32 + lk * 8);
  }
#pragma unroll
  for (int tt = 6; tt < 8; ++tt) {
    int row = 3 * 256 + wv * 32 + (tt & 1) * 16 + lm;
    int s = wv * 2 + (tt - 6);
#pragma unroll
    for (int ks = 0; ks < 8; ++ks) {
      short8 w = pack8f(Wrec + (size_t)row * 256 + ks * 32 + lk * 8);
      *(short8*)&wlds[((s * 8 + ks) * 64 + l) * 8] = w;
    }
  }
  __syncthreads();

  int e_nxt = 0;
  if (LAYER == 0) e_nxt = eidx[bb * LSEQ];  // e for t=0 (always -1)
  unsigned Tc0 = 0, Tc1 = 0;

  for (int t = 0; t < LSEQ; ++t) {
    const int rd = ((t + 1) & 1) * HT1;  // h(t-1) buffer
    const int wr = (t & 1) * HT1;        // h(t) buffer
    // ---- per-lane input gates: vv[g] = 4 bf16 at (bb, gate g, jj..jj+3) ----
    uint2 vv[4];
    if (LAYER == 0) {
      const uint2* vp = (const uint2*)(vpn + (size_t)t * 1024);
      const int j4 = jj >> 2;
#pragma unroll
      for (int g = 0; g < 4; ++g) vv[g] = vp[g * 64 + j4];
      int e = e_nxt;
      if (t + 1 < LSEQ) e_nxt = eidx[bb * LSEQ + t + 1];  // prefetch next
      if (e >= 0) {
        const uint2* cp = (const uint2*)(corr + (size_t)e * 1024);
#pragma unroll
        for (int g = 0; g < 4; ++g) {
          uint2 cv = cp[g * 64 + j4];
          vv[g].x = addbf2(vv[g].x, cv.x);
          vv[g].y = addbf2(vv[g].y, cv.y);
        }
      }
    } else {
      unsigned Tm = (Tc0 < Tc1) ? Tc0 : Tc1;
      while (Tm < (unsigned)(t + 1)) {
        Tc0 = aload(flags + FLAG_H0);
        Tc1 = aload(flags + FLAG_H1);
        Tm = (Tc0 < Tc1) ? Tc0 : Tc1;
        if (--budget == 0) break;
        asm volatile("s_sleep 1");
      }
      cbar();
      const unsigned long long* ub =
          (const unsigned long long*)(uring + (size_t)(t & (RINGSZ - 1)) * 4096 + bb * 512);
      const int j2q = jj >> 2;  // quad (4 bf16) index within the 256-wide gate block
#pragma unroll
      for (int g = 0; g < 4; ++g) {
        unsigned long long q = aload64(ub + g * 64 + j2q);
        vv[g].x = (unsigned)q;
        vv[g].y = (unsigned)(q >> 32);
      }
    }

    // ---- MFMA phase: ks-major, 8 independent acc chains ----
    float4e acc[8];
#pragma unroll
    for (int tt = 0; tt < 8; ++tt) acc[tt] = (float4e){0.f, 0.f, 0.f, 0.f};
    __builtin_amdgcn_s_setprio(1);
#pragma unroll
    for (int ks = 0; ks < 8; ++ks) {
      short8 hb = *(const short8*)(hT + rd + lmr * HST + ks * 32 + lk * 8);
      short8 w6 = *(const short8*)&wlds[(((wv * 2 + 0) * 8 + ks) * 64 + l) * 8];
      short8 w7 = *(const short8*)&wlds[(((wv * 2 + 1) * 8 + ks) * 64 + l) * 8];
#pragma unroll
      for (int tt = 0; tt < 6; ++tt) acc[tt] = MFMA16(wf[tt][ks], hb, acc[tt]);
      acc[6] = MFMA16(w6, hb, acc[6]);
      acc[7] = MFMA16(w7, hb, acc[7]);
    }
    __builtin_amdgcn_s_setprio(0);

    // ---- gather gates into owning lane: pair-1 accs shuffle to lanes lm>=8 ----
    float gt[4][4];
#pragma unroll
    for (int g = 0; g < 4; ++g) {
      float4e aP0 = acc[(g < 3) ? 2 * g : 6];
      float4e aP1 = acc[(g < 3) ? 2 * g + 1 : 7];
      float vf0 = blo(vv[g].x), vf1 = bhi(vv[g].x);
      float vf2 = blo(vv[g].y), vf3 = bhi(vv[g].y);
#pragma unroll
      for (int r = 0; r < 4; ++r) {
        float sh = __shfl_xor(aP1[r], 8);
        float base = (lm < 8) ? aP0[r] : sh;
        float vf = (r == 0) ? vf0 : (r == 1) ? vf1 : (r == 2) ? vf2 : vf3;
        gt[g][r] = base + vf;
      }
    }
    // ---- in-register LSTM update: lane owns (bb, jj..jj+3), c in VGPRs ----
    float hv[4];
#pragma unroll
    for (int r = 0; r < 4; ++r) {
      float cn = sigf(gt[1][r]) * cc[r] + sigf(gt[0][r]) * tanhf2(gt[2][r]);
      cc[r] = cn;
      hv[r] = sigf(gt[3][r]) * tanhf2(cn);
    }
    unsigned h01 = (unsigned)f2bf(hv[0]) | ((unsigned)f2bf(hv[1]) << 16);
    unsigned h23 = (unsigned)f2bf(hv[2]) | ((unsigned)f2bf(hv[3]) << 16);
    *(uint2*)&hT[wr + bb * HST + jj] = make_uint2(h01, h23);
    astore64((unsigned long long*)(hout + (size_t)(t + 1) * 1024 + bb * 128 + (jj >> 1)),
             (unsigned long long)h01 | ((unsigned long long)h23 << 32));

    // ---- single barrier/step; flag publish every 8 (L0) / 64 (L1) ----
    if (LAYER == 0) {
      if ((t & 7) == 7) fencev();
      barrier_lgkm();
      if ((t & 7) == 7 && tid == 0) astore(flags + FLAG_R0, (unsigned)(t + 1));
    } else {
      barrier_lgkm();
      if ((t & 63) == 63 && tid == 0) astore(flags + PROG_R1, (unsigned)(t + 1));
    }
  }
}

// uprod: LDS-staged, double-buffered, register-prefetched; ONE barrier/step.
// Per step: stage hw (h0(t+2), loaded last step) into write buffer, read
// B-fragments for h0(t+1) from read buffer, MFMA, ring store, then prefetch
// h0(t+3) (latency hides across the barrier: barrier_lgkm drains lgkm only).
static __device__ __forceinline__ void uprod(
    int hid, const float* __restrict__ Wih1, unsigned* flags,
    const unsigned* __restrict__ h0w, unsigned* uring, unsigned short* hB, int tid) {
  const int wv = tid >> 6, l = tid & 63, lm = l & 15, lk = l >> 4;
  const int lmr = (lm < 8) ? lm : 8;
  unsigned budget = 20000000u;
  for (int i = tid; i < 2 * HT1; i += 512) hB[i] = 0;
  short8 wf[4][8];
#pragma unroll
  for (int tt = 0; tt < 4; ++tt) {
    int row = hid * 512 + (wv * 4 + tt) * 16 + lm;
#pragma unroll
    for (int ks = 0; ks < 8; ++ks)
      wf[tt][ks] = pack8f(Wih1 + (size_t)row * 256 + ks * 32 + lk * 8);
  }
  __syncthreads();
  unsigned Fc = 0, Pc = 0;
  // prologue: buf0 <- h0(1); hw <- h0(2)
  while (Fc < 2u) {
    Fc = aload(flags + FLAG_R0);
    if (--budget == 0) break;
    asm volatile("s_sleep 1");
  }
  cbar();
  {
    uint2 t0 = ((const uint2*)(h0w + (size_t)1 * 1024))[tid];
    *(uint2*)((unsigned*)hB + wv * (HST / 2) + l * 2) = t0;
  }
  uint2 hw = ((const uint2*)(h0w + (size_t)2 * 1024))[tid];
  barrier_lgkm();
  for (int t = 0; t < LSEQ; ++t) {
    const int rdo = (t & 1) * HT1;
    const int wro = ((t + 1) & 1) * HT1;
    if (t + 1 < LSEQ)
      *(uint2*)((unsigned*)(hB + wro) + wv * (HST / 2) + l * 2) = hw;
    short8 bfr[8];
#pragma unroll
    for (int ks = 0; ks < 8; ++ks)
      bfr[ks] = *(const short8*)(hB + rdo + lmr * HST + ks * 32 + lk * 8);
    float4e a[4];
#pragma unroll
    for (int tt = 0; tt < 4; ++tt) a[tt] = (float4e){0.f, 0.f, 0.f, 0.f};
    __builtin_amdgcn_s_setprio(1);
#pragma unroll
    for (int ks = 0; ks < 8; ++ks) {
#pragma unroll
      for (int tt = 0; tt < 4; ++tt) a[tt] = MFMA16(wf[tt][ks], bfr[ks], a[tt]);
    }
    __builtin_amdgcn_s_setprio(0);
    int slot = t & (RINGSZ - 1);
    if (lm < 8) {
#pragma unroll
      for (int tt = 0; tt < 4; ++tt) {
        int g0 = hid * 512 + (wv * 4 + tt) * 16 + lk * 4;
        unsigned p0 = (unsigned)f2bf(a[tt][0]) | ((unsigned)f2bf(a[tt][1]) << 16);
        unsigned p1 = (unsigned)f2bf(a[tt][2]) | ((unsigned)f2bf(a[tt][3]) << 16);
        unsigned* up = uring + (size_t)slot * 4096 + lm * 512 + (g0 >> 1);
        astore(up, p0);
        astore(up + 1, p1);
      }
    }
    if (t + 2 < LSEQ) {
      while (Fc < (unsigned)(t + 3)) {  // h0 slot t+3 published?
        Fc = aload(flags + FLAG_R0);
        if (--budget == 0) break;
        asm volatile("s_sleep 1");
      }
      while ((unsigned)(t + 1) >= Pc + 448u) {  // ring back-pressure
        Pc = aload(flags + PROG_R1);
        if (--budget == 0) break;
        asm volatile("s_sleep 1");
      }
      cbar();
      hw = ((const uint2*)(h0w + (size_t)(t + 3) * 1024))[tid];
    }
    if ((t & 7) == 7) fencev();
    barrier_lgkm();
    if ((t & 7) == 7 && tid == 0)
      astore(flags + (hid ? FLAG_H1 : FLAG_H0), (unsigned)(t + 1));
  }
}

__global__ __launch_bounds__(512, 1) void k_lstm(
    const float* __restrict__ Whh0, const float* __restrict__ Wih1,
    const float* __restrict__ Whh1, const unsigned short* __restrict__ vpn,
    const int* __restrict__ eidx, const unsigned short* __restrict__ corr,
    const float* __restrict__ inith, const float* __restrict__ initc,
    unsigned* flags, unsigned* uring, unsigned* h0w, unsigned* h1w) {
  __shared__ __align__(16) short wlds[16 * 8 * 64 * 8];       // 131072 B
  __shared__ __align__(16) unsigned short hT[2 * HT1];        // 9504 B -> 140576 total
  const int tid = threadIdx.x;
  const int bx = blockIdx.x;
  if (bx == 0)
    recur<0>(Whh0, vpn, eidx, corr, nullptr, inith, initc, flags, h0w, wlds, hT, tid);
  else if (bx == 1)
    recur<1>(Whh1, nullptr, nullptr, nullptr, uring, inith, initc, flags, h1w, wlds, hT, tid);
  else
    uprod(bx - 2, Wih1, flags, h0w, uring, hT, tid);
}

// ---- heads (unchanged) ----
__global__ __launch_bounds__(256, 2) void k_heads(
    const unsigned short* __restrict__ h1u, const float* __restrict__ xadj,
    const float* __restrict__ lgW1, const float* __restrict__ lgb1,
    const float* __restrict__ lgW2, const float* __restrict__ lgb2,
    const float* __restrict__ muW1, const float* __restrict__ mub1,
    const float* __restrict__ muW2, const float* __restrict__ mub2,
    const float* __restrict__ vaW1, const float* __restrict__ vab1,
    const float* __restrict__ vaW2, const float* __restrict__ vab2,
    float* dout) {
  __shared__ float vals[4][3][64];
  const int tid = threadIdx.x;
  const int v = tid >> 6, l = tid & 63, lm = l & 15, lk = l >> 4;
  const int wid = blockIdx.x * 4 + v;
  const int m0 = wid * 64;

  short8 afr[4][8];
#pragma unroll
  for (int tt = 0; tt < 4; ++tt)
#pragma unroll
    for (int ks = 0; ks < 8; ++ks)
      afr[tt][ks] = *(const short8*)(h1u + (size_t)(m0 + tt * 16 + lm) * 256 + 2048 + ks * 32 + lk * 8);

  const float* W1s[3] = {lgW1, muW1, vaW1};
  const float* b1s[3] = {lgb1, mub1, vab1};
  const float* W2s[3] = {lgW2, muW2, vaW2};

  for (int h = 0; h < 3; ++h) {
    float accr[4][4];
#pragma unroll
    for (int tt = 0; tt < 4; ++tt)
#pragma unroll
      for (int r = 0; r < 4; ++r) accr[tt][r] = 0.f;
    const float* W1p = W1s[h];
    const float* b1p = b1s[h];
    const float* W2p = W2s[h];
    for (int nt = 0; nt < 32; ++nt) {
      float4e c0 = {0.f, 0.f, 0.f, 0.f}, c1 = c0, c2 = c0, c3 = c0;
      const float* wp = W1p + (size_t)(nt * 16 + lm) * 256;
#pragma unroll
      for (int ks = 0; ks < 8; ++ks) {
        short8 bfr = pack8f(wp + ks * 32 + lk * 8);
        c0 = MFMA16(afr[0][ks], bfr, c0);
        c1 = MFMA16(afr[1][ks], bfr, c1);
        c2 = MFMA16(afr[2][ks], bfr, c2);
        c3 = MFMA16(afr[3][ks], bfr, c3);
      }
      float bias = b1p[nt * 16 + lm], w2v = W2p[nt * 16 + lm];
#pragma unroll
      for (int r = 0; r < 4; ++r) {
        accr[0][r] += fmaxf(c0[r] + bias, 0.f) * w2v;
        accr[1][r] += fmaxf(c1[r] + bias, 0.f) * w2v;
        accr[2][r] += fmaxf(c2[r] + bias, 0.f) * w2v;
        accr[3][r] += fmaxf(c3[r] + bias, 0.f) * w2v;
      }
    }
#pragma unroll
    for (int tt = 0; tt < 4; ++tt)
#pragma unroll
      for (int r = 0; r < 4; ++r) {
        float a2 = accr[tt][r];
        a2 += __shfl_xor(a2, 1);
        a2 += __shfl_xor(a2, 2);
        a2 += __shfl_xor(a2, 4);
        a2 += __shfl_xor(a2, 8);
        if (lm == 0) vals[v][h][tt * 16 + lk * 4 + r] = a2;
      }
  }
  __syncthreads();
  {
    int m = m0 + l;
    int tq = m >> 3, b = m & 7;
    float z = vals[v][0][l] + lgb2[0];
    float mu = vals[v][1][l] + mub2[0];
    float lv = vals[v][2][l] + vab2[0];
    float x = xadj[(size_t)b * LSEQ + tq];
    float xt = (x > 0.f) ? 1.f : 0.f;
    float lr = fmaxf(z, 0.f) - z * xt + log1pf(expf(-fabsf(z)));
    float lw = 0.f;
    if (x > 0.f) {
      float sm = (x > 20.f) ? x : logf(expm1f(fminf(x, 20.f)));
      float d = mu - sm;
      lw = 0.5f * (lv + d * d * expf(-lv));
    }
#pragma unroll
    for (int d2 = 1; d2 < 64; d2 <<= 1) {
      lr += __shfl_xor(lr, d2);
      lw += __shfl_xor(lw, d2);
    }
    if (l == 0) {
      atomicAdd(dout + 0, lr * (1.f / 1024.f));
      atomicAdd(dout + 1, lw * (1.f / 1024.f));
    }
  }
}

extern "C" void kernel_launch(void* const* d_in, const int* in_sizes, int n_in,
                              void* d_out, int out_size, void* d_ws, size_t ws_size,
                              hipStream_t stream) {
  const float* x_adj = (const float*)d_in[0];
  const float* ee    = (const float*)d_in[1];
  const float* nemb  = (const float*)d_in[2];
  const float* ewW1  = (const float*)d_in[3];
  const float* ewb1  = (const float*)d_in[4];
  const float* ewW2  = (const float*)d_in[5];
  const float* ewb2  = (const float*)d_in[6];
  const float* Wih0  = (const float*)d_in[7];
  const float* Whh0  = (const float*)d_in[8];
  const float* Wih1  = (const float*)d_in[9];
  const float* Whh1  = (const float*)d_in[10];
  const float* muW1  = (const float*)d_in[11];
  const float* mub1  = (const float*)d_in[12];
  const float* muW2  = (const float*)d_in[13];
  const float* mub2  = (const float*)d_in[14];
  const float* vaW1  = (const float*)d_in[15];
  const float* vab1  = (const float*)d_in[16];
  const float* vaW2  = (const float*)d_in[17];
  const float* vab2  = (const float*)d_in[18];
  const float* lgW1  = (const float*)d_in[19];
  const float* lgb1  = (const float*)d_in[20];
  const float* lgW2  = (const float*)d_in[21];
  const float* lgb2  = (const float*)d_in[22];
  const float* inith = (const float*)d_in[23];
  const float* initc = (const float*)d_in[24];

  char* wsb = (char*)d_ws;
  unsigned* flags      = (unsigned*)wsb;
  unsigned* counter    = (unsigned*)(wsb + 512);
  float* P             = (float*)(wsb + WS_P);
  float* aee           = (float*)(wsb + WS_AEE);
  unsigned short* vpn  = (unsigned short*)(wsb + WS_VPN);
  int* eidx            = (int*)(wsb + WS_EIDX);
  unsigned short* corr = (unsigned short*)(wsb + WS_CORR);
  unsigned* uring      = (unsigned*)(wsb + WS_URING);
  unsigned* h0w        = (unsigned*)(wsb + WS_H0);
  unsigned* h1w        = (unsigned*)(wsb + WS_H1);
  unsigned short* h0u  = (unsigned short*)(wsb + WS_H0);
  unsigned short* h1u  = (unsigned short*)(wsb + WS_H1);

  (void)in_sizes; (void)n_in; (void)ws_size;

  hipMemsetAsync(d_ws, 0, 4096, stream);
  hipMemsetAsync(d_out, 0, (size_t)out_size * 4, stream);

  k_prep_P<<<512, 256, 0, stream>>>(Wih0, ewW2, P);
  k_prep_aee_init<<<8, 256, 0, stream>>>(Wih0, ee, ewb1, ewb2, P, inith, aee, h0u, h1u);
  k_prep_vpn<<<LSEQ, 256, 0, stream>>>(Wih0, nemb, aee, vpn);
  k_prep_eidx<<<(NB * LSEQ) / 256, 256, 0, stream>>>(x_adj, eidx, counter);
  k_prep_corr<<<NB * LSEQ, 256, 0, stream>>>(x_adj, ewW1, ewb1, P, aee, eidx, corr);
  k_lstm<<<4, 512, 0, stream>>>(Whh0, Wih1, Whh1, vpn, eidx, corr, inith, initc,
                                flags, uring, h0w, h1w);
  k_heads<<<254, 256, 0, stream>>>(h1u, x_adj, lgW1, lgb1, lgW2, lgb2,
                                   muW1, mub1, muW2, mub2, vaW1, vab1, vaW2, vab2,
                                   (float*)d_out);
}

// Round 3
// 28933.969 us; speedup vs baseline: 1.3995x; 1.3551x over previous
//
#include <hip/hip_runtime.h>

#define LSEQ 8128
#define NB 8
#define CORR_CAP 8192
#define HST 264          // hT row stride (shorts); 528 B spreads banks
#define HROWS 9          // 8 batch rows + 1 shared zero row (lm>=8 broadcast)
#define HT1 (HROWS * HST)
#define RINGSZ 512
// flag dword offsets (128B apart; counter moved to +2048 to avoid overlap)
#define FLAG_R0A 0
#define FLAG_R0B 32
#define FLAG_R1A 64
#define FLAG_R1B 96
#define FLAG_H(q) (128 + (q) * 32)

typedef __attribute__((ext_vector_type(8))) short short8;
typedef __attribute__((ext_vector_type(4))) float float4e;

#define MFMA16(a, b, c) __builtin_amdgcn_mfma_f32_16x16x32_bf16((a), (b), (c), 0, 0, 0)

// ---- workspace layout (bytes) ----
#define WS_P      4096ul
#define WS_AEE    528384ul
#define WS_VPN    536576ul      // bf16 [8128][1024]
#define WS_EIDX   17182720ul
#define WS_CORR   17444864ul    // bf16 [8192][1024]
#define WS_URING  34222080ul    // bf16 ring [512][8][1024]
#define WS_H0     42610688ul    // bf16 [8129][8][256]
#define WS_H1     75907072ul

static __device__ __forceinline__ unsigned short f2bf(float f) {
  unsigned u = __float_as_uint(f);
  return (unsigned short)((u + 0x7fffu + ((u >> 16) & 1u)) >> 16);  // RNE
}
static __device__ __forceinline__ float blo(unsigned u) { return __uint_as_float(u << 16); }
static __device__ __forceinline__ float bhi(unsigned u) { return __uint_as_float(u & 0xffff0000u); }
static __device__ __forceinline__ unsigned addbf2(unsigned a, unsigned b) {
  float lo = blo(a) + blo(b), hi = bhi(a) + bhi(b);
  return (unsigned)f2bf(lo) | ((unsigned)f2bf(hi) << 16);
}
static __device__ __forceinline__ short8 pack8f(const float* __restrict__ p) {
  short8 r;
#pragma unroll
  for (int i = 0; i < 8; ++i) r[i] = (short)f2bf(p[i]);
  return r;
}
static __device__ __forceinline__ unsigned aload(const unsigned* p) {
  return __hip_atomic_load(p, __ATOMIC_RELAXED, __HIP_MEMORY_SCOPE_AGENT);
}
static __device__ __forceinline__ void astore(unsigned* p, unsigned v) {
  __hip_atomic_store(p, v, __ATOMIC_RELAXED, __HIP_MEMORY_SCOPE_AGENT);
}
static __device__ __forceinline__ unsigned long long aload64(const unsigned long long* p) {
  return __hip_atomic_load(p, __ATOMIC_RELAXED, __HIP_MEMORY_SCOPE_AGENT);
}
static __device__ __forceinline__ void astore64(unsigned long long* p, unsigned long long v) {
  __hip_atomic_store(p, v, __ATOMIC_RELAXED, __HIP_MEMORY_SCOPE_AGENT);
}
static __device__ __forceinline__ void fencev() {
  asm volatile("s_waitcnt vmcnt(0)" ::: "memory");
}
static __device__ __forceinline__ void cbar() { asm volatile("" ::: "memory"); }
static __device__ __forceinline__ void barrier_lgkm() {
  asm volatile("s_waitcnt lgkmcnt(0)\ns_barrier" ::: "memory");
}
static __device__ __forceinline__ float sigf(float x) { return 1.f / (1.f + __expf(-x)); }
static __device__ __forceinline__ float tanhf2(float x) { return 2.f / (1.f + __expf(-2.f * x)) - 1.f; }

// ---- preps (unchanged except counter location) ----
__global__ void k_prep_P(const float* __restrict__ Wih0, const float* __restrict__ ewW2,
                         float* __restrict__ P) {
  int idx = blockIdx.x * 256 + threadIdx.x;
  int g = idx >> 7, k = idx & 127;
  const float* wr = Wih0 + (size_t)g * 320 + 128;
  float s = 0.f;
#pragma unroll 8
  for (int j = 0; j < 64; ++j) s += wr[j] * ewW2[j * 128 + k];
  P[idx] = s;
}

__global__ void k_prep_aee_init(const float* __restrict__ Wih0, const float* __restrict__ ee,
                                const float* __restrict__ b1, const float* __restrict__ b2,
                                const float* __restrict__ P, const float* __restrict__ inith,
                                float* __restrict__ aee, unsigned short* __restrict__ h0u,
                                unsigned short* __restrict__ h1u) {
  int idx = blockIdx.x * 256 + threadIdx.x;  // < 2048
  int s = idx >> 10, g = idx & 1023;
  const float* wr = Wih0 + (size_t)g * 320;
  float a = 0.f;
#pragma unroll 8
  for (int i = 0; i < 128; ++i) a += wr[i] * ee[s * 128 + i];
#pragma unroll 8
  for (int j = 0; j < 64; ++j) a += wr[128 + j] * b2[j];
  const float* pr = P + (size_t)g * 128;
#pragma unroll 8
  for (int k = 0; k < 128; ++k) a += pr[k] * fmaxf(b1[k], 0.f);
  aee[s * 1024 + g] = a;
  unsigned short hv = f2bf(inith[idx & 127]);
  h0u[idx] = hv;
  h1u[idx] = hv;
}

__global__ void k_prep_vpn(const float* __restrict__ Wih0, const float* __restrict__ nemb,
                           const float* __restrict__ aee, unsigned short* __restrict__ vpn) {
  __shared__ float pn[128];
  int t = blockIdx.x, tid = threadIdx.x;
  if (tid < 32) {
    float div = expf(-9.2103403719761836f * (float)(2 * tid) / 64.f);
    float ang = (float)t * div;
    pn[2 * tid] = sinf(ang);
    pn[2 * tid + 1] = cosf(ang);
  } else if (tid < 96) {
    int r = (int)((1.f + sqrtf(8.f * (float)t + 1.f)) * 0.5f);
    while (r * (r + 1) / 2 <= t) ++r;
    while (r * (r - 1) / 2 > t) --r;
    pn[64 + (tid - 32)] = nemb[r * 64 + (tid - 32)];
  }
  __syncthreads();
#pragma unroll
  for (int rr = 0; rr < 4; ++rr) {
    int row = rr * 256 + tid;
    const float* wr = Wih0 + (size_t)row * 320 + 192;
    float s = 0.f;
#pragma unroll 8
    for (int i = 0; i < 128; ++i) s += wr[i] * pn[i];
    vpn[(size_t)t * 1024 + row] = f2bf(s + aee[row]);
  }
}

__global__ void k_prep_eidx(const float* __restrict__ xadj, int* __restrict__ eidx,
                            unsigned* __restrict__ counter) {
  int idx = blockIdx.x * 256 + threadIdx.x;
  if (idx >= NB * LSEQ) return;
  int t = idx % LSEQ;
  int e = -1;
  if (t > 0 && xadj[idx - 1] > 0.f) {
    e = (int)atomicAdd(counter, 1u);
    if (e >= CORR_CAP) e = -1;
  }
  eidx[idx] = e;
}

__global__ void k_prep_corr(const float* __restrict__ xadj, const float* __restrict__ w1,
                            const float* __restrict__ b1, const float* __restrict__ P,
                            const float* __restrict__ aee, const int* __restrict__ eidx,
                            unsigned short* __restrict__ corr) {
  __shared__ float rh[128];
  int bid = blockIdx.x;
  int e = eidx[bid];
  if (e < 0) return;
  int tid = threadIdx.x;
  float wt = xadj[bid - 1];
  if (tid < 128) {
    float bb = b1[tid];
    rh[tid] = fmaxf(wt * w1[tid] + bb, 0.f) - fmaxf(bb, 0.f);
  }
  __syncthreads();
#pragma unroll
  for (int rr = 0; rr < 4; ++rr) {
    int row = rr * 256 + tid;
    const float* pr = P + (size_t)row * 128;
    float s = 0.f;
#pragma unroll 8
    for (int k = 0; k < 128; ++k) s += pr[k] * rh[k];
    corr[(size_t)e * 1024 + row] = f2bf(s + aee[1024 + row] - aee[row]);
  }
}

// ============ split-CU persistent recurrence ============
// Each layer runs on TWO CUs (halves H=0/1 of the 256-wide hidden dim).
// Wave wv owns j-slice [base + wv*16, +16) for ALL 4 gates -> wf[4][8] =
// 128 VGPRs/lane, fully register-resident (the whole point: kills the
// per-step 512KB L2/scratch weight stream that was the 3.4us/step wall).
// Per step: X = MFMAs over own-half K (h computed locally last step),
// then poll partner flag, load partner's h-half from global (L3), stage
// into hT, barrier, Z = MFMAs over remote-half K, lane-local LSTM update.
// Two barriers/step, per-step flag publish after vmcnt drain.
template <int LAYER, int H>
static __device__ __forceinline__ void recur(
    const float* __restrict__ Wrec, const unsigned short* __restrict__ vpn,
    const int* __restrict__ eidx, const unsigned short* __restrict__ corr,
    const unsigned* __restrict__ uring, const float* __restrict__ inith,
    const float* __restrict__ initc, unsigned* flags, unsigned* hout,
    unsigned short* hT, int tid, int myflag, int rflag) {
  const int wv = tid >> 6, l = tid & 63, lm = l & 15, lk = l >> 4;
  const int lmr = (lm < 8) ? lm : 8;   // lanes 8-15 broadcast the zero row (B operand)
  const int base = H * 128;
  const int rbase = 128 - base;
  const int jg = base + wv * 16 + lk * 4;  // owned global j (4 cols), batch = lm (<8)
  unsigned budget = 20000000u;

  for (int i = tid; i < HT1; i += 512) hT[i] = 0;
  __syncthreads();
  {  // rows 0-7 = inith tiled; row 8 stays zero
    int b = tid >> 6, j0i = (tid & 63) * 4;
    unsigned h01 = (unsigned)f2bf(inith[j0i & 127]) | ((unsigned)f2bf(inith[(j0i + 1) & 127]) << 16);
    unsigned h23 = (unsigned)f2bf(inith[(j0i + 2) & 127]) | ((unsigned)f2bf(inith[(j0i + 3) & 127]) << 16);
    *(uint2*)&hT[b * HST + j0i] = make_uint2(h01, h23);
  }
  float cc[4];
#pragma unroll
  for (int r = 0; r < 4; ++r) cc[r] = initc[(jg + r) & 127];

  // 4 gate-tiles, ALL K, in registers (gate-major rows g*256 + j)
  short8 wf[4][8];
#pragma unroll
  for (int g = 0; g < 4; ++g) {
    int row = g * 256 + base + wv * 16 + lm;
#pragma unroll
    for (int ks = 0; ks < 8; ++ks)
      wf[g][ks] = pack8f(Wrec + (size_t)row * 256 + ks * 32 + lk * 8);
  }
  __syncthreads();

  int e_nxt = (LAYER == 0 && lm < 8) ? eidx[lm * LSEQ] : -1;
  unsigned Rc = 0, Tm = 0;

  for (int t = 0; t < LSEQ; ++t) {
    float4e acc[4];
#pragma unroll
    for (int g = 0; g < 4; ++g) acc[g] = (float4e){0.f, 0.f, 0.f, 0.f};
    // ---- X: own-half K ----
    __builtin_amdgcn_s_setprio(1);
#pragma unroll
    for (int ksl = 0; ksl < 4; ++ksl) {
      const int ks = H * 4 + ksl;
      short8 hb = *(const short8*)(hT + lmr * HST + ks * 32 + lk * 8);
#pragma unroll
      for (int g = 0; g < 4; ++g) acc[g] = MFMA16(wf[g][ks], hb, acc[g]);
    }
    __builtin_amdgcn_s_setprio(0);
    // ---- partner's h(t-1) half: poll flag >= t, then load (t=0: h*w[0]=init) ----
    while (Rc < (unsigned)t) {
      Rc = aload(flags + rflag);
      if (--budget == 0) break;
      asm volatile("s_sleep 1");
    }
    cbar();
    const int fb = tid >> 6, fj = rbase + (tid & 63) * 2;
    unsigned fill = hout[(size_t)t * 1024 + fb * 128 + (fj >> 1)];
    // ---- per-lane input gates (overlap the fill load's L3 RTT) ----
    uint2 vv[4];
    if (LAYER == 0) {
      if (lm < 8) {
        const uint2* vp = (const uint2*)(vpn + (size_t)t * 1024);
#pragma unroll
        for (int g = 0; g < 4; ++g) vv[g] = vp[(g * 256 + jg) >> 2];
        int e = e_nxt;
        if (t + 1 < LSEQ) e_nxt = eidx[lm * LSEQ + t + 1];
        if (e >= 0) {
          const uint2* cp = (const uint2*)(corr + (size_t)e * 1024);
#pragma unroll
          for (int g = 0; g < 4; ++g) {
            uint2 cv = cp[(g * 256 + jg) >> 2];
            vv[g].x = addbf2(vv[g].x, cv.x);
            vv[g].y = addbf2(vv[g].y, cv.y);
          }
        }
      }
    } else {
      while (Tm < (unsigned)(t + 1)) {
        unsigned c0 = aload(flags + FLAG_H(0)), c1 = aload(flags + FLAG_H(1));
        unsigned c2 = aload(flags + FLAG_H(2)), c3 = aload(flags + FLAG_H(3));
        unsigned m0 = c0 < c1 ? c0 : c1, m1 = c2 < c3 ? c2 : c3;
        Tm = m0 < m1 ? m0 : m1;
        if (--budget == 0) break;
        asm volatile("s_sleep 1");
      }
      cbar();
      if (lm < 8) {
        const unsigned long long* ub =
            (const unsigned long long*)(uring + (size_t)(t & (RINGSZ - 1)) * 4096 + lm * 512);
#pragma unroll
        for (int g = 0; g < 4; ++g) {
          unsigned long long qv = aload64(ub + ((g * 256 + jg) >> 2));
          vv[g].x = (unsigned)qv;
          vv[g].y = (unsigned)(qv >> 32);
        }
      }
    }
    // ---- stage remote half into hT; barrier; Z: remote-half K ----
    *(unsigned*)&hT[fb * HST + fj] = fill;
    barrier_lgkm();
    __builtin_amdgcn_s_setprio(1);
#pragma unroll
    for (int ksl = 0; ksl < 4; ++ksl) {
      const int ks = (4 - H * 4) + ksl;
      short8 hb = *(const short8*)(hT + lmr * HST + ks * 32 + lk * 8);
#pragma unroll
      for (int g = 0; g < 4; ++g) acc[g] = MFMA16(wf[g][ks], hb, acc[g]);
    }
    __builtin_amdgcn_s_setprio(0);
    // ---- lane-local update: lane (lm<8, lk) owns (batch lm, j = jg..jg+3) ----
    if (lm < 8) {
      float gt[4][4];
#pragma unroll
      for (int g = 0; g < 4; ++g) {
        gt[g][0] = acc[g][0] + blo(vv[g].x);
        gt[g][1] = acc[g][1] + bhi(vv[g].x);
        gt[g][2] = acc[g][2] + blo(vv[g].y);
        gt[g][3] = acc[g][3] + bhi(vv[g].y);
      }
      float hv[4];
#pragma unroll
      for (int r = 0; r < 4; ++r) {
        float cn = sigf(gt[1][r]) * cc[r] + sigf(gt[0][r]) * tanhf2(gt[2][r]);
        cc[r] = cn;
        hv[r] = sigf(gt[3][r]) * tanhf2(cn);
      }
      unsigned h01 = (unsigned)f2bf(hv[0]) | ((unsigned)f2bf(hv[1]) << 16);
      unsigned h23 = (unsigned)f2bf(hv[2]) | ((unsigned)f2bf(hv[3]) << 16);
      *(uint2*)&hT[lm * HST + jg] = make_uint2(h01, h23);  // local cols only; X/Z read disjoint/barriered
      astore64((unsigned long long*)(hout + (size_t)(t + 1) * 1024 + lm * 128 + (jg >> 1)),
               (unsigned long long)h01 | ((unsigned long long)h23 << 32));
    }
    fencev();         // drain own h store before flag can be published
    barrier_lgkm();
    if (tid == 0) astore(flags + myflag, (unsigned)(t + 1));
  }
}

// uprod quarter q: gate q's 256 rows of Wih1, wf[2][8] = 64 VGPRs/lane
// (register-resident). LDS-staged double-buffered h0, register prefetch
// t+3, one barrier/step. Gated on min(L0A,L0B) per-step flags.
static __device__ __forceinline__ void uprod(
    int q, const float* __restrict__ Wih1, unsigned* flags,
    const unsigned* __restrict__ h0w, unsigned* uring, unsigned short* hB, int tid) {
  const int wv = tid >> 6, l = tid & 63, lm = l & 15, lk = l >> 4;
  const int lmr = (lm < 8) ? lm : 8;
  unsigned budget = 20000000u;
  for (int i = tid; i < 2 * HT1; i += 512) hB[i] = 0;
  short8 wf[2][8];
#pragma unroll
  for (int tt = 0; tt < 2; ++tt) {
    int row = q * 256 + (wv * 2 + tt) * 16 + lm;
#pragma unroll
    for (int ks = 0; ks < 8; ++ks)
      wf[tt][ks] = pack8f(Wih1 + (size_t)row * 256 + ks * 32 + lk * 8);
  }
  __syncthreads();
  unsigned FcA = 0, FcB = 0, Fm = 0, PcA = 0, PcB = 0, Pm = 0;
  while (Fm < 2u) {
    FcA = aload(flags + FLAG_R0A);
    FcB = aload(flags + FLAG_R0B);
    Fm = FcA < FcB ? FcA : FcB;
    if (--budget == 0) break;
    asm volatile("s_sleep 1");
  }
  cbar();
  {
    uint2 t0 = ((const uint2*)(h0w + (size_t)1 * 1024))[tid];
    *(uint2*)((unsigned*)hB + wv * (HST / 2) + l * 2) = t0;
  }
  uint2 hw = ((const uint2*)(h0w + (size_t)2 * 1024))[tid];
  barrier_lgkm();
  for (int t = 0; t < LSEQ; ++t) {
    const int rdo = (t & 1) * HT1;
    const int wro = ((t + 1) & 1) * HT1;
    if (t + 1 < LSEQ)
      *(uint2*)((unsigned*)(hB + wro) + wv * (HST / 2) + l * 2) = hw;
    short8 bfr[8];
#pragma unroll
    for (int ks = 0; ks < 8; ++ks)
      bfr[ks] = *(const short8*)(hB + rdo + lmr * HST + ks * 32 + lk * 8);
    float4e a0 = {0.f, 0.f, 0.f, 0.f}, a1 = a0;
    __builtin_amdgcn_s_setprio(1);
#pragma unroll
    for (int ks = 0; ks < 8; ++ks) {
      a0 = MFMA16(wf[0][ks], bfr[ks], a0);
      a1 = MFMA16(wf[1][ks], bfr[ks], a1);
    }
    __builtin_amdgcn_s_setprio(0);
    int slot = t & (RINGSZ - 1);
    if (lm < 8) {
#pragma unroll
      for (int tt = 0; tt < 2; ++tt) {
        float4e a = tt ? a1 : a0;
        int g0 = q * 256 + (wv * 2 + tt) * 16 + lk * 4;
        unsigned p0 = (unsigned)f2bf(a[0]) | ((unsigned)f2bf(a[1]) << 16);
        unsigned p1 = (unsigned)f2bf(a[2]) | ((unsigned)f2bf(a[3]) << 16);
        unsigned* up = uring + (size_t)slot * 4096 + lm * 512 + (g0 >> 1);
        astore(up, p0);
        astore(up + 1, p1);
      }
    }
    if (t + 2 < LSEQ) {
      while (Fm < (unsigned)(t + 3)) {
        FcA = aload(flags + FLAG_R0A);
        FcB = aload(flags + FLAG_R0B);
        Fm = FcA < FcB ? FcA : FcB;
        if (--budget == 0) break;
        asm volatile("s_sleep 1");
      }
      while ((unsigned)(t + 1) >= Pm + 448u) {  // ring back-pressure
        PcA = aload(flags + FLAG_R1A);
        PcB = aload(flags + FLAG_R1B);
        Pm = PcA < PcB ? PcA : PcB;
        if (--budget == 0) break;
        asm volatile("s_sleep 1");
      }
      cbar();
      hw = ((const uint2*)(h0w + (size_t)(t + 3) * 1024))[tid];
    }
    if ((t & 7) == 7) fencev();
    barrier_lgkm();
    if ((t & 7) == 7 && tid == 0)
      astore(flags + FLAG_H(q), (unsigned)(t + 1));
  }
}

__global__ __launch_bounds__(512, 2) void k_lstm(
    const float* __restrict__ Whh0, const float* __restrict__ Wih1,
    const float* __restrict__ Whh1, const unsigned short* __restrict__ vpn,
    const int* __restrict__ eidx, const unsigned short* __restrict__ corr,
    const float* __restrict__ inith, const float* __restrict__ initc,
    unsigned* flags, unsigned* uring, unsigned* h0w, unsigned* h1w) {
  __shared__ __align__(16) unsigned short hT[2 * HT1];  // 9504 B total LDS
  const int tid = threadIdx.x;
  const int bx = blockIdx.x;
  if (bx == 0)
    recur<0, 0>(Whh0, vpn, eidx, corr, nullptr, inith, initc, flags, h0w, hT, tid,
                FLAG_R0A, FLAG_R0B);
  else if (bx == 1)
    recur<0, 1>(Whh0, vpn, eidx, corr, nullptr, inith, initc, flags, h0w, hT, tid,
                FLAG_R0B, FLAG_R0A);
  else if (bx == 2)
    recur<1, 0>(Whh1, nullptr, nullptr, nullptr, uring, inith, initc, flags, h1w, hT, tid,
                FLAG_R1A, FLAG_R1B);
  else if (bx == 3)
    recur<1, 1>(Whh1, nullptr, nullptr, nullptr, uring, inith, initc, flags, h1w, hT, tid,
                FLAG_R1B, FLAG_R1A);
  else
    uprod(bx - 4, Wih1, flags, h0w, uring, hT, tid);
}

// ---- heads (unchanged) ----
__global__ __launch_bounds__(256, 2) void k_heads(
    const unsigned short* __restrict__ h1u, const float* __restrict__ xadj,
    const float* __restrict__ lgW1, const float* __restrict__ lgb1,
    const float* __restrict__ lgW2, const float* __restrict__ lgb2,
    const float* __restrict__ muW1, const float* __restrict__ mub1,
    const float* __restrict__ muW2, const float* __restrict__ mub2,
    const float* __restrict__ vaW1, const float* __restrict__ vab1,
    const float* __restrict__ vaW2, const float* __restrict__ vab2,
    float* dout) {
  __shared__ float vals[4][3][64];
  const int tid = threadIdx.x;
  const int v = tid >> 6, l = tid & 63, lm = l & 15, lk = l >> 4;
  const int wid = blockIdx.x * 4 + v;
  const int m0 = wid * 64;

  short8 afr[4][8];
#pragma unroll
  for (int tt = 0; tt < 4; ++tt)
#pragma unroll
    for (int ks = 0; ks < 8; ++ks)
      afr[tt][ks] = *(const short8*)(h1u + (size_t)(m0 + tt * 16 + lm) * 256 + 2048 + ks * 32 + lk * 8);

  const float* W1s[3] = {lgW1, muW1, vaW1};
  const float* b1s[3] = {lgb1, mub1, vab1};
  const float* W2s[3] = {lgW2, muW2, vaW2};

  for (int h = 0; h < 3; ++h) {
    float accr[4][4];
#pragma unroll
    for (int tt = 0; tt < 4; ++tt)
#pragma unroll
      for (int r = 0; r < 4; ++r) accr[tt][r] = 0.f;
    const float* W1p = W1s[h];
    const float* b1p = b1s[h];
    const float* W2p = W2s[h];
    for (int nt = 0; nt < 32; ++nt) {
      float4e c0 = {0.f, 0.f, 0.f, 0.f}, c1 = c0, c2 = c0, c3 = c0;
      const float* wp = W1p + (size_t)(nt * 16 + lm) * 256;
#pragma unroll
      for (int ks = 0; ks < 8; ++ks) {
        short8 bfr = pack8f(wp + ks * 32 + lk * 8);
        c0 = MFMA16(afr[0][ks], bfr, c0);
        c1 = MFMA16(afr[1][ks], bfr, c1);
        c2 = MFMA16(afr[2][ks], bfr, c2);
        c3 = MFMA16(afr[3][ks], bfr, c3);
      }
      float bias = b1p[nt * 16 + lm], w2v = W2p[nt * 16 + lm];
#pragma unroll
      for (int r = 0; r < 4; ++r) {
        accr[0][r] += fmaxf(c0[r] + bias, 0.f) * w2v;
        accr[1][r] += fmaxf(c1[r] + bias, 0.f) * w2v;
        accr[2][r] += fmaxf(c2[r] + bias, 0.f) * w2v;
        accr[3][r] += fmaxf(c3[r] + bias, 0.f) * w2v;
      }
    }
#pragma unroll
    for (int tt = 0; tt < 4; ++tt)
#pragma unroll
      for (int r = 0; r < 4; ++r) {
        float a2 = accr[tt][r];
        a2 += __shfl_xor(a2, 1);
        a2 += __shfl_xor(a2, 2);
        a2 += __shfl_xor(a2, 4);
        a2 += __shfl_xor(a2, 8);
        if (lm == 0) vals[v][h][tt * 16 + lk * 4 + r] = a2;
      }
  }
  __syncthreads();
  {
    int m = m0 + l;
    int tq = m >> 3, b = m & 7;
    float z = vals[v][0][l] + lgb2[0];
    float mu = vals[v][1][l] + mub2[0];
    float lv = vals[v][2][l] + vab2[0];
    float x = xadj[(size_t)b * LSEQ + tq];
    float xt = (x > 0.f) ? 1.f : 0.f;
    float lr = fmaxf(z, 0.f) - z * xt + log1pf(expf(-fabsf(z)));
    float lw = 0.f;
    if (x > 0.f) {
      float sm = (x > 20.f) ? x : logf(expm1f(fminf(x, 20.f)));
      float d = mu - sm;
      lw = 0.5f * (lv + d * d * expf(-lv));
    }
#pragma unroll
    for (int d2 = 1; d2 < 64; d2 <<= 1) {
      lr += __shfl_xor(lr, d2);
      lw += __shfl_xor(lw, d2);
    }
    if (l == 0) {
      atomicAdd(dout + 0, lr * (1.f / 1024.f));
      atomicAdd(dout + 1, lw * (1.f / 1024.f));
    }
  }
}

extern "C" void kernel_launch(void* const* d_in, const int* in_sizes, int n_in,
                              void* d_out, int out_size, void* d_ws, size_t ws_size,
                              hipStream_t stream) {
  const float* x_adj = (const float*)d_in[0];
  const float* ee    = (const float*)d_in[1];
  const float* nemb  = (const float*)d_in[2];
  const float* ewW1  = (const float*)d_in[3];
  const float* ewb1  = (const float*)d_in[4];
  const float* ewW2  = (const float*)d_in[5];
  const float* ewb2  = (const float*)d_in[6];
  const float* Wih0  = (const float*)d_in[7];
  const float* Whh0  = (const float*)d_in[8];
  const float* Wih1  = (const float*)d_in[9];
  const float* Whh1  = (const float*)d_in[10];
  const float* muW1  = (const float*)d_in[11];
  const float* mub1  = (const float*)d_in[12];
  const float* muW2  = (const float*)d_in[13];
  const float* mub2  = (const float*)d_in[14];
  const float* vaW1  = (const float*)d_in[15];
  const float* vab1  = (const float*)d_in[16];
  const float* vaW2  = (const float*)d_in[17];
  const float* vab2  = (const float*)d_in[18];
  const float* lgW1  = (const float*)d_in[19];
  const float* lgb1  = (const float*)d_in[20];
  const float* lgW2  = (const float*)d_in[21];
  const float* lgb2  = (const float*)d_in[22];
  const float* inith = (const float*)d_in[23];
  const float* initc = (const float*)d_in[24];

  char* wsb = (char*)d_ws;
  unsigned* flags      = (unsigned*)wsb;                 // dwords [0, 256)
  unsigned* counter    = (unsigned*)(wsb + 2048);        // moved past flag block
  float* P             = (float*)(wsb + WS_P);
  float* aee           = (float*)(wsb + WS_AEE);
  unsigned short* vpn  = (unsigned short*)(wsb + WS_VPN);
  int* eidx            = (int*)(wsb + WS_EIDX);
  unsigned short* corr = (unsigned short*)(wsb + WS_CORR);
  unsigned* uring      = (unsigned*)(wsb + WS_URING);
  unsigned* h0w        = (unsigned*)(wsb + WS_H0);
  unsigned* h1w        = (unsigned*)(wsb + WS_H1);
  unsigned short* h0u  = (unsigned short*)(wsb + WS_H0);
  unsigned short* h1u  = (unsigned short*)(wsb + WS_H1);

  (void)in_sizes; (void)n_in; (void)ws_size;

  hipMemsetAsync(d_ws, 0, 4096, stream);
  hipMemsetAsync(d_out, 0, (size_t)out_size * 4, stream);

  k_prep_P<<<512, 256, 0, stream>>>(Wih0, ewW2, P);
  k_prep_aee_init<<<8, 256, 0, stream>>>(Wih0, ee, ewb1, ewb2, P, inith, aee, h0u, h1u);
  k_prep_vpn<<<LSEQ, 256, 0, stream>>>(Wih0, nemb, aee, vpn);
  k_prep_eidx<<<(NB * LSEQ) / 256, 256, 0, stream>>>(x_adj, eidx, counter);
  k_prep_corr<<<NB * LSEQ, 256, 0, stream>>>(x_adj, ewW1, ewb1, P, aee, eidx, corr);
  k_lstm<<<8, 512, 0, stream>>>(Whh0, Wih1, Whh1, vpn, eidx, corr, inith, initc,
                                flags, uring, h0w, h1w);
  k_heads<<<254, 256, 0, stream>>>(h1u, x_adj, lgW1, lgb1, lgW2, lgb2,
                                   muW1, mub1, muW2, mub2, vaW1, vab1, vaW2, vab2,
                                   (float*)d_out);
}

// Round 4
// 26899.683 us; speedup vs baseline: 1.5054x; 1.0756x over previous
//
#include <hip/hip_runtime.h>

#define LSEQ 8128
#define NB 8
#define CORR_CAP 8192
#define HST 264          // hT row stride (shorts); 528 B spreads banks
#define HROWS 9          // 8 batch rows + 1 shared zero row (lm>=8 broadcast)
#define HT1 (HROWS * HST)
#define RINGSZ 256
// flag dword offsets (128B apart; counter at +2048)
#define FLAG_R0A 0
#define FLAG_R0B 32
#define FLAG_R1A 64
#define FLAG_R1B 96
#define FLAG_H(q) (128 + (q) * 32)

typedef __attribute__((ext_vector_type(8))) short short8;
typedef __attribute__((ext_vector_type(4))) float float4e;

#define MFMA16(a, b, c) __builtin_amdgcn_mfma_f32_16x16x32_bf16((a), (b), (c), 0, 0, 0)

// ---- workspace layout (bytes) ----
#define WS_P      4096ul
#define WS_AEE    528384ul
#define WS_VPN    536576ul      // bf16 [8128][1024]
#define WS_EIDX   17182720ul
#define WS_CORR   17444864ul    // bf16 [8192][1024]
#define WS_URING  34222080ul    // bf16 ring [256][8][1024] (4 MB)
#define WS_HX     38416384ul    // tagged h-exchange: 16 regions x 4 KB = 64 KB
#define WS_H0     42610688ul    // bf16 [8129][8][256]
#define WS_H1     75907072ul

static __device__ __forceinline__ unsigned short f2bf(float f) {
  unsigned u = __float_as_uint(f);
  return (unsigned short)((u + 0x7fffu + ((u >> 16) & 1u)) >> 16);  // RNE
}
static __device__ __forceinline__ float blo(unsigned u) { return __uint_as_float(u << 16); }
static __device__ __forceinline__ float bhi(unsigned u) { return __uint_as_float(u & 0xffff0000u); }
static __device__ __forceinline__ short8 pack8f(const float* __restrict__ p) {
  short8 r;
#pragma unroll
  for (int i = 0; i < 8; ++i) r[i] = (short)f2bf(p[i]);
  return r;
}
static __device__ __forceinline__ unsigned aload(const unsigned* p) {
  return __hip_atomic_load(p, __ATOMIC_RELAXED, __HIP_MEMORY_SCOPE_AGENT);
}
static __device__ __forceinline__ void astore(unsigned* p, unsigned v) {
  __hip_atomic_store(p, v, __ATOMIC_RELAXED, __HIP_MEMORY_SCOPE_AGENT);
}
static __device__ __forceinline__ unsigned long long aload64(const unsigned long long* p) {
  return __hip_atomic_load(p, __ATOMIC_RELAXED, __HIP_MEMORY_SCOPE_AGENT);
}
static __device__ __forceinline__ void astore64(unsigned long long* p, unsigned long long v) {
  __hip_atomic_store(p, v, __ATOMIC_RELAXED, __HIP_MEMORY_SCOPE_AGENT);
}
static __device__ __forceinline__ void fencev() {
  asm volatile("s_waitcnt vmcnt(0)" ::: "memory");
}
static __device__ __forceinline__ void cbar() { asm volatile("" ::: "memory"); }
static __device__ __forceinline__ void barrier_lgkm() {
  asm volatile("s_waitcnt lgkmcnt(0)\ns_barrier" ::: "memory");
}
static __device__ __forceinline__ float sigf(float x) { return 1.f / (1.f + __expf(-x)); }
static __device__ __forceinline__ float tanhf2(float x) { return 2.f / (1.f + __expf(-2.f * x)) - 1.f; }

// ---- preps (unchanged) ----
__global__ void k_prep_P(const float* __restrict__ Wih0, const float* __restrict__ ewW2,
                         float* __restrict__ P) {
  int idx = blockIdx.x * 256 + threadIdx.x;
  int g = idx >> 7, k = idx & 127;
  const float* wr = Wih0 + (size_t)g * 320 + 128;
  float s = 0.f;
#pragma unroll 8
  for (int j = 0; j < 64; ++j) s += wr[j] * ewW2[j * 128 + k];
  P[idx] = s;
}

__global__ void k_prep_aee_init(const float* __restrict__ Wih0, const float* __restrict__ ee,
                                const float* __restrict__ b1, const float* __restrict__ b2,
                                const float* __restrict__ P, const float* __restrict__ inith,
                                float* __restrict__ aee, unsigned short* __restrict__ h0u,
                                unsigned short* __restrict__ h1u) {
  int idx = blockIdx.x * 256 + threadIdx.x;  // < 2048
  int s = idx >> 10, g = idx & 1023;
  const float* wr = Wih0 + (size_t)g * 320;
  float a = 0.f;
#pragma unroll 8
  for (int i = 0; i < 128; ++i) a += wr[i] * ee[s * 128 + i];
#pragma unroll 8
  for (int j = 0; j < 64; ++j) a += wr[128 + j] * b2[j];
  const float* pr = P + (size_t)g * 128;
#pragma unroll 8
  for (int k = 0; k < 128; ++k) a += pr[k] * fmaxf(b1[k], 0.f);
  aee[s * 1024 + g] = a;
  unsigned short hv = f2bf(inith[idx & 127]);
  h0u[idx] = hv;
  h1u[idx] = hv;
}

__global__ void k_prep_vpn(const float* __restrict__ Wih0, const float* __restrict__ nemb,
                           const float* __restrict__ aee, unsigned short* __restrict__ vpn) {
  __shared__ float pn[128];
  int t = blockIdx.x, tid = threadIdx.x;
  if (tid < 32) {
    float div = expf(-9.2103403719761836f * (float)(2 * tid) / 64.f);
    float ang = (float)t * div;
    pn[2 * tid] = sinf(ang);
    pn[2 * tid + 1] = cosf(ang);
  } else if (tid < 96) {
    int r = (int)((1.f + sqrtf(8.f * (float)t + 1.f)) * 0.5f);
    while (r * (r + 1) / 2 <= t) ++r;
    while (r * (r - 1) / 2 > t) --r;
    pn[64 + (tid - 32)] = nemb[r * 64 + (tid - 32)];
  }
  __syncthreads();
#pragma unroll
  for (int rr = 0; rr < 4; ++rr) {
    int row = rr * 256 + tid;
    const float* wr = Wih0 + (size_t)row * 320 + 192;
    float s = 0.f;
#pragma unroll 8
    for (int i = 0; i < 128; ++i) s += wr[i] * pn[i];
    vpn[(size_t)t * 1024 + row] = f2bf(s + aee[row]);
  }
}

__global__ void k_prep_eidx(const float* __restrict__ xadj, int* __restrict__ eidx,
                            unsigned* __restrict__ counter) {
  int idx = blockIdx.x * 256 + threadIdx.x;
  if (idx >= NB * LSEQ) return;
  int t = idx % LSEQ;
  int e = -1;
  if (t > 0 && xadj[idx - 1] > 0.f) {
    e = (int)atomicAdd(counter, 1u);
    if (e >= CORR_CAP) e = -1;
  }
  eidx[idx] = e;
}

__global__ void k_prep_corr(const float* __restrict__ xadj, const float* __restrict__ w1,
                            const float* __restrict__ b1, const float* __restrict__ P,
                            const float* __restrict__ aee, const int* __restrict__ eidx,
                            unsigned short* __restrict__ corr) {
  __shared__ float rh[128];
  int bid = blockIdx.x;
  int e = eidx[bid];
  if (e < 0) return;
  int tid = threadIdx.x;
  float wt = xadj[bid - 1];
  if (tid < 128) {
    float bb = b1[tid];
    rh[tid] = fmaxf(wt * w1[tid] + bb, 0.f) - fmaxf(bb, 0.f);
  }
  __syncthreads();
#pragma unroll
  for (int rr = 0; rr < 4; ++rr) {
    int row = rr * 256 + tid;
    const float* pr = P + (size_t)row * 128;
    float s = 0.f;
#pragma unroll 8
    for (int k = 0; k < 128; ++k) s += pr[k] * rh[k];
    corr[(size_t)e * 1024 + row] = f2bf(s + aee[1024 + row] - aee[row]);
  }
}

// ============ split-CU persistent recurrence with tagged 1-RTT exchange ============
// Two CUs per layer (hidden halves). Per step: issue inputs (top, hidden under
// X), X = own-half-K MFMAs, poll tagged remote chunk (data+tag in ONE 8B
// atomic word -> one LLC RTT, no flag, no fence), stage, barrier, Z =
// remote-half-K MFMAs, lane-local f32 gather + LSTM update, tagged store.
template <int LAYER, int H>
static __device__ __forceinline__ void recur(
    const float* __restrict__ Wrec, const unsigned short* __restrict__ vpn,
    const int* __restrict__ eidx, const unsigned short* __restrict__ corr,
    const unsigned* __restrict__ uring, const float* __restrict__ inith,
    const float* __restrict__ initc, unsigned* flags, unsigned* hout,
    unsigned long long* hx, unsigned short* hT, int tid, int myflag) {
  const int wv = tid >> 6, l = tid & 63, lm = l & 15, lk = l >> 4;
  const int lmr = (lm < 8) ? lm : 8;   // lanes 8-15 broadcast the zero row (B operand)
  const int base = H * 128;
  const int rbase = 128 - base;
  const int jg = base + wv * 16 + lk * 4;  // owned global j (4 cols), batch = lm (<8)
  unsigned budget = 100000000u;

  unsigned long long* hx_my = hx + (size_t)((LAYER * 2 + H) * 4) * 512;
  const unsigned long long* hx_rm = hx + (size_t)((LAYER * 2 + (1 - H)) * 4) * 512;
  const int myc = lm * 64 + wv * 8 + lk * 2;  // producer chunks myc, myc+1 (lm<8)
  const int fb = tid >> 6, fl = tid & 63;
  const int rmc = fb * 64 + fl;               // consumer chunk
  const int fj = rbase + fl * 2;              // staged remote cols (2 shorts)

  for (int i = tid; i < HT1; i += 512) hT[i] = 0;
  __syncthreads();
  {  // rows 0-7 = inith tiled over 256 cols; row 8 stays zero
    int b = tid >> 6, j0i = (tid & 63) * 4;
    unsigned h01 = (unsigned)f2bf(inith[j0i & 127]) | ((unsigned)f2bf(inith[(j0i + 1) & 127]) << 16);
    unsigned h23 = (unsigned)f2bf(inith[(j0i + 2) & 127]) | ((unsigned)f2bf(inith[(j0i + 3) & 127]) << 16);
    *(uint2*)&hT[b * HST + j0i] = make_uint2(h01, h23);
  }
  float cc[4];
#pragma unroll
  for (int r = 0; r < 4; ++r) cc[r] = initc[(jg + r) & 127];

  // 4 gate-tiles, ALL K, register-resident (gate-major rows g*256 + j)
  short8 wf[4][8];
#pragma unroll
  for (int g = 0; g < 4; ++g) {
    int row = g * 256 + base + wv * 16 + lm;
#pragma unroll
    for (int ks = 0; ks < 8; ++ks)
      wf[g][ks] = pack8f(Wrec + (size_t)row * 256 + ks * 32 + lk * 8);
  }
  __syncthreads();

  int e_nxt = (LAYER == 0 && lm < 8) ? eidx[lm * LSEQ] : -1;
  unsigned Tm = 0;

  for (int t = 0; t < LSEQ; ++t) {
    // ---- input issue at loop TOP (latency hides under X) ----
    uint2 vv[4], cv[4];
#pragma unroll
    for (int g = 0; g < 4; ++g) { vv[g] = make_uint2(0u, 0u); cv[g] = make_uint2(0u, 0u); }
    if (LAYER == 0) {
      if (lm < 8) {
        const uint2* vp = (const uint2*)(vpn + (size_t)t * 1024);
#pragma unroll
        for (int g = 0; g < 4; ++g) vv[g] = vp[(g * 256 + jg) >> 2];
        int e = e_nxt;
        if (t + 1 < LSEQ) e_nxt = eidx[lm * LSEQ + t + 1];
        if (e >= 0) {
          const uint2* cp = (const uint2*)(corr + (size_t)e * 1024);
#pragma unroll
          for (int g = 0; g < 4; ++g) cv[g] = cp[(g * 256 + jg) >> 2];
        }
      }
    } else {
      while (Tm < (unsigned)(t + 1)) {
        unsigned c0 = aload(flags + FLAG_H(0)), c1 = aload(flags + FLAG_H(1));
        unsigned c2 = aload(flags + FLAG_H(2)), c3 = aload(flags + FLAG_H(3));
        unsigned m0 = c0 < c1 ? c0 : c1, m1 = c2 < c3 ? c2 : c3;
        Tm = m0 < m1 ? m0 : m1;
        if (--budget == 0) break;
        asm volatile("s_sleep 1");
      }
      cbar();
      if (lm < 8) {
        const unsigned long long* ub =
            (const unsigned long long*)(uring + (size_t)(t & (RINGSZ - 1)) * 4096 + lm * 512);
#pragma unroll
        for (int g = 0; g < 4; ++g) {
          unsigned long long qv = aload64(ub + ((g * 256 + jg) >> 2));
          vv[g].x = (unsigned)qv;
          vv[g].y = (unsigned)(qv >> 32);
        }
      }
    }

    // ---- X: own-half K ----
    float4e acc[4];
#pragma unroll
    for (int g = 0; g < 4; ++g) acc[g] = (float4e){0.f, 0.f, 0.f, 0.f};
    __builtin_amdgcn_s_setprio(1);
#pragma unroll
    for (int ksl = 0; ksl < 4; ++ksl) {
      const int ks = H * 4 + ksl;
      short8 hb = *(const short8*)(hT + lmr * HST + ks * 32 + lk * 8);
#pragma unroll
      for (int g = 0; g < 4; ++g) acc[g] = MFMA16(wf[g][ks], hb, acc[g]);
    }
    __builtin_amdgcn_s_setprio(0);

    // ---- exchange: poll tagged chunk (ONE RTT; data+tag atomic) ----
    if (t > 0) {
      unsigned long long q;
      do {
        q = aload64(hx_rm + (size_t)(t & 3) * 512 + rmc);
        if (--budget == 0) break;
      } while ((unsigned)(q >> 32) != (unsigned)t);
      cbar();
      *(unsigned*)&hT[fb * HST + fj] = (unsigned)q;
    }
    barrier_lgkm();

    // ---- Z: remote-half K ----
    __builtin_amdgcn_s_setprio(1);
#pragma unroll
    for (int ksl = 0; ksl < 4; ++ksl) {
      const int ks = (4 - H * 4) + ksl;
      short8 hb = *(const short8*)(hT + lmr * HST + ks * 32 + lk * 8);
#pragma unroll
      for (int g = 0; g < 4; ++g) acc[g] = MFMA16(wf[g][ks], hb, acc[g]);
    }
    __builtin_amdgcn_s_setprio(0);

    // ---- lane-local f32 gather + LSTM update ----
    if (lm < 8) {
      float gt[4][4];
#pragma unroll
      for (int g = 0; g < 4; ++g) {
        gt[g][0] = acc[g][0] + blo(vv[g].x) + (LAYER == 0 ? blo(cv[g].x) : 0.f);
        gt[g][1] = acc[g][1] + bhi(vv[g].x) + (LAYER == 0 ? bhi(cv[g].x) : 0.f);
        gt[g][2] = acc[g][2] + blo(vv[g].y) + (LAYER == 0 ? blo(cv[g].y) : 0.f);
        gt[g][3] = acc[g][3] + bhi(vv[g].y) + (LAYER == 0 ? bhi(cv[g].y) : 0.f);
      }
      float hv[4];
#pragma unroll
      for (int r = 0; r < 4; ++r) {
        float cn = sigf(gt[1][r]) * cc[r] + sigf(gt[0][r]) * tanhf2(gt[2][r]);
        cc[r] = cn;
        hv[r] = sigf(gt[3][r]) * tanhf2(cn);
      }
      unsigned h01 = (unsigned)f2bf(hv[0]) | ((unsigned)f2bf(hv[1]) << 16);
      unsigned h23 = (unsigned)f2bf(hv[2]) | ((unsigned)f2bf(hv[3]) << 16);
      *(uint2*)&hT[lm * HST + jg] = make_uint2(h01, h23);  // local cols; disjoint from Z reads
      astore64((unsigned long long*)(hout + (size_t)(t + 1) * 1024 + lm * 128 + (jg >> 1)),
               (unsigned long long)h01 | ((unsigned long long)h23 << 32));
      unsigned long long tg = ((unsigned long long)(unsigned)(t + 1)) << 32;
      unsigned long long* hs = hx_my + (size_t)((t + 1) & 3) * 512 + myc;
      astore64(hs, (unsigned long long)h01 | tg);
      astore64(hs + 1, (unsigned long long)h23 | tg);
    }

    // ---- epilogue: barrier; sparse fenced flag publish ----
    if (LAYER == 0) {
      if ((t & 3) == 3) fencev();
      barrier_lgkm();
      if ((t & 3) == 3 && tid == 0) astore(flags + myflag, (unsigned)(t + 1));
    } else {
      if ((t & 63) == 63) fencev();
      barrier_lgkm();
      if ((t & 63) == 63 && tid == 0) astore(flags + myflag, (unsigned)(t + 1));
    }
  }
}

// uprod quarter q: gate q's 256 rows of Wih1, wf[2][8] register-resident.
// LDS-staged double-buffered h0, register prefetch t+3, one barrier/step.
static __device__ __forceinline__ void uprod(
    int q, const float* __restrict__ Wih1, unsigned* flags,
    const unsigned* __restrict__ h0w, unsigned* uring, unsigned short* hB, int tid) {
  const int wv = tid >> 6, l = tid & 63, lm = l & 15, lk = l >> 4;
  const int lmr = (lm < 8) ? lm : 8;
  unsigned budget = 100000000u;
  for (int i = tid; i < 2 * HT1; i += 512) hB[i] = 0;
  short8 wf[2][8];
#pragma unroll
  for (int tt = 0; tt < 2; ++tt) {
    int row = q * 256 + (wv * 2 + tt) * 16 + lm;
#pragma unroll
    for (int ks = 0; ks < 8; ++ks)
      wf[tt][ks] = pack8f(Wih1 + (size_t)row * 256 + ks * 32 + lk * 8);
  }
  __syncthreads();
  unsigned FcA = 0, FcB = 0, Fm = 0, PcA = 0, PcB = 0, Pm = 0;
  while (Fm < 2u) {
    FcA = aload(flags + FLAG_R0A);
    FcB = aload(flags + FLAG_R0B);
    Fm = FcA < FcB ? FcA : FcB;
    if (--budget == 0) break;
    asm volatile("s_sleep 1");
  }
  cbar();
  {
    uint2 t0 = ((const uint2*)(h0w + (size_t)1 * 1024))[tid];
    *(uint2*)((unsigned*)hB + wv * (HST / 2) + l * 2) = t0;
  }
  uint2 hw = ((const uint2*)(h0w + (size_t)2 * 1024))[tid];
  barrier_lgkm();
  for (int t = 0; t < LSEQ; ++t) {
    const int rdo = (t & 1) * HT1;
    const int wro = ((t + 1) & 1) * HT1;
    if (t + 1 < LSEQ)
      *(uint2*)((unsigned*)(hB + wro) + wv * (HST / 2) + l * 2) = hw;
    short8 bfr[8];
#pragma unroll
    for (int ks = 0; ks < 8; ++ks)
      bfr[ks] = *(const short8*)(hB + rdo + lmr * HST + ks * 32 + lk * 8);
    float4e a0 = {0.f, 0.f, 0.f, 0.f}, a1 = a0;
    __builtin_amdgcn_s_setprio(1);
#pragma unroll
    for (int ks = 0; ks < 8; ++ks) {
      a0 = MFMA16(wf[0][ks], bfr[ks], a0);
      a1 = MFMA16(wf[1][ks], bfr[ks], a1);
    }
    __builtin_amdgcn_s_setprio(0);
    int slot = t & (RINGSZ - 1);
    if (lm < 8) {
#pragma unroll
      for (int tt = 0; tt < 2; ++tt) {
        float4e a = tt ? a1 : a0;
        int g0 = q * 256 + (wv * 2 + tt) * 16 + lk * 4;
        unsigned p0 = (unsigned)f2bf(a[0]) | ((unsigned)f2bf(a[1]) << 16);
        unsigned p1 = (unsigned)f2bf(a[2]) | ((unsigned)f2bf(a[3]) << 16);
        unsigned* up = uring + (size_t)slot * 4096 + lm * 512 + (g0 >> 1);
        astore(up, p0);
        astore(up + 1, p1);
      }
    }
    if (t + 2 < LSEQ) {
      while (Fm < (unsigned)(t + 3)) {
        FcA = aload(flags + FLAG_R0A);
        FcB = aload(flags + FLAG_R0B);
        Fm = FcA < FcB ? FcA : FcB;
        if (--budget == 0) break;
        asm volatile("s_sleep 1");
      }
      while ((unsigned)(t + 1) >= Pm + 192u) {  // ring back-pressure (256 slots)
        PcA = aload(flags + FLAG_R1A);
        PcB = aload(flags + FLAG_R1B);
        Pm = PcA < PcB ? PcA : PcB;
        if (--budget == 0) break;
        asm volatile("s_sleep 1");
      }
      cbar();
      hw = ((const uint2*)(h0w + (size_t)(t + 3) * 1024))[tid];
    }
    if ((t & 7) == 7) fencev();
    barrier_lgkm();
    if ((t & 7) == 7 && tid == 0)
      astore(flags + FLAG_H(q), (unsigned)(t + 1));
  }
}

__global__ __launch_bounds__(512, 2) void k_lstm(
    const float* __restrict__ Whh0, const float* __restrict__ Wih1,
    const float* __restrict__ Whh1, const unsigned short* __restrict__ vpn,
    const int* __restrict__ eidx, const unsigned short* __restrict__ corr,
    const float* __restrict__ inith, const float* __restrict__ initc,
    unsigned* flags, unsigned* uring, unsigned long long* hx,
    unsigned* h0w, unsigned* h1w) {
  __shared__ __align__(16) unsigned short hT[2 * HT1];  // 9504 B total LDS
  const int tid = threadIdx.x;
  const int bx = blockIdx.x;
  if (bx == 0)
    recur<0, 0>(Whh0, vpn, eidx, corr, nullptr, inith, initc, flags, h0w, hx, hT, tid, FLAG_R0A);
  else if (bx == 1)
    recur<0, 1>(Whh0, vpn, eidx, corr, nullptr, inith, initc, flags, h0w, hx, hT, tid, FLAG_R0B);
  else if (bx == 2)
    recur<1, 0>(Whh1, nullptr, nullptr, nullptr, uring, inith, initc, flags, h1w, hx, hT, tid, FLAG_R1A);
  else if (bx == 3)
    recur<1, 1>(Whh1, nullptr, nullptr, nullptr, uring, inith, initc, flags, h1w, hx, hT, tid, FLAG_R1B);
  else
    uprod(bx - 4, Wih1, flags, h0w, uring, hT, tid);
}

// ---- heads (unchanged) ----
__global__ __launch_bounds__(256, 2) void k_heads(
    const unsigned short* __restrict__ h1u, const float* __restrict__ xadj,
    const float* __restrict__ lgW1, const float* __restrict__ lgb1,
    const float* __restrict__ lgW2, const float* __restrict__ lgb2,
    const float* __restrict__ muW1, const float* __restrict__ mub1,
    const float* __restrict__ muW2, const float* __restrict__ mub2,
    const float* __restrict__ vaW1, const float* __restrict__ vab1,
    const float* __restrict__ vaW2, const float* __restrict__ vab2,
    float* dout) {
  __shared__ float vals[4][3][64];
  const int tid = threadIdx.x;
  const int v = tid >> 6, l = tid & 63, lm = l & 15, lk = l >> 4;
  const int wid = blockIdx.x * 4 + v;
  const int m0 = wid * 64;

  short8 afr[4][8];
#pragma unroll
  for (int tt = 0; tt < 4; ++tt)
#pragma unroll
    for (int ks = 0; ks < 8; ++ks)
      afr[tt][ks] = *(const short8*)(h1u + (size_t)(m0 + tt * 16 + lm) * 256 + 2048 + ks * 32 + lk * 8);

  const float* W1s[3] = {lgW1, muW1, vaW1};
  const float* b1s[3] = {lgb1, mub1, vab1};
  const float* W2s[3] = {lgW2, muW2, vaW2};

  for (int h = 0; h < 3; ++h) {
    float accr[4][4];
#pragma unroll
    for (int tt = 0; tt < 4; ++tt)
#pragma unroll
      for (int r = 0; r < 4; ++r) accr[tt][r] = 0.f;
    const float* W1p = W1s[h];
    const float* b1p = b1s[h];
    const float* W2p = W2s[h];
    for (int nt = 0; nt < 32; ++nt) {
      float4e c0 = {0.f, 0.f, 0.f, 0.f}, c1 = c0, c2 = c0, c3 = c0;
      const float* wp = W1p + (size_t)(nt * 16 + lm) * 256;
#pragma unroll
      for (int ks = 0; ks < 8; ++ks) {
        short8 bfr = pack8f(wp + ks * 32 + lk * 8);
        c0 = MFMA16(afr[0][ks], bfr, c0);
        c1 = MFMA16(afr[1][ks], bfr, c1);
        c2 = MFMA16(afr[2][ks], bfr, c2);
        c3 = MFMA16(afr[3][ks], bfr, c3);
      }
      float bias = b1p[nt * 16 + lm], w2v = W2p[nt * 16 + lm];
#pragma unroll
      for (int r = 0; r < 4; ++r) {
        accr[0][r] += fmaxf(c0[r] + bias, 0.f) * w2v;
        accr[1][r] += fmaxf(c1[r] + bias, 0.f) * w2v;
        accr[2][r] += fmaxf(c2[r] + bias, 0.f) * w2v;
        accr[3][r] += fmaxf(c3[r] + bias, 0.f) * w2v;
      }
    }
#pragma unroll
    for (int tt = 0; tt < 4; ++tt)
#pragma unroll
      for (int r = 0; r < 4; ++r) {
        float a2 = accr[tt][r];
        a2 += __shfl_xor(a2, 1);
        a2 += __shfl_xor(a2, 2);
        a2 += __shfl_xor(a2, 4);
        a2 += __shfl_xor(a2, 8);
        if (lm == 0) vals[v][h][tt * 16 + lk * 4 + r] = a2;
      }
  }
  __syncthreads();
  {
    int m = m0 + l;
    int tq = m >> 3, b = m & 7;
    float z = vals[v][0][l] + lgb2[0];
    float mu = vals[v][1][l] + mub2[0];
    float lv = vals[v][2][l] + vab2[0];
    float x = xadj[(size_t)b * LSEQ + tq];
    float xt = (x > 0.f) ? 1.f : 0.f;
    float lr = fmaxf(z, 0.f) - z * xt + log1pf(expf(-fabsf(z)));
    float lw = 0.f;
    if (x > 0.f) {
      float sm = (x > 20.f) ? x : logf(expm1f(fminf(x, 20.f)));
      float d = mu - sm;
      lw = 0.5f * (lv + d * d * expf(-lv));
    }
#pragma unroll
    for (int d2 = 1; d2 < 64; d2 <<= 1) {
      lr += __shfl_xor(lr, d2);
      lw += __shfl_xor(lw, d2);
    }
    if (l == 0) {
      atomicAdd(dout + 0, lr * (1.f / 1024.f));
      atomicAdd(dout + 1, lw * (1.f / 1024.f));
    }
  }
}

extern "C" void kernel_launch(void* const* d_in, const int* in_sizes, int n_in,
                              void* d_out, int out_size, void* d_ws, size_t ws_size,
                              hipStream_t stream) {
  const float* x_adj = (const float*)d_in[0];
  const float* ee    = (const float*)d_in[1];
  const float* nemb  = (const float*)d_in[2];
  const float* ewW1  = (const float*)d_in[3];
  const float* ewb1  = (const float*)d_in[4];
  const float* ewW2  = (const float*)d_in[5];
  const float* ewb2  = (const float*)d_in[6];
  const float* Wih0  = (const float*)d_in[7];
  const float* Whh0  = (const float*)d_in[8];
  const float* Wih1  = (const float*)d_in[9];
  const float* Whh1  = (const float*)d_in[10];
  const float* muW1  = (const float*)d_in[11];
  const float* mub1  = (const float*)d_in[12];
  const float* muW2  = (const float*)d_in[13];
  const float* mub2  = (const float*)d_in[14];
  const float* vaW1  = (const float*)d_in[15];
  const float* vab1  = (const float*)d_in[16];
  const float* vaW2  = (const float*)d_in[17];
  const float* vab2  = (const float*)d_in[18];
  const float* lgW1  = (const float*)d_in[19];
  const float* lgb1  = (const float*)d_in[20];
  const float* lgW2  = (const float*)d_in[21];
  const float* lgb2  = (const float*)d_in[22];
  const float* inith = (const float*)d_in[23];
  const float* initc = (const float*)d_in[24];

  char* wsb = (char*)d_ws;
  unsigned* flags      = (unsigned*)wsb;                 // dwords [0, 256)
  unsigned* counter    = (unsigned*)(wsb + 2048);
  float* P             = (float*)(wsb + WS_P);
  float* aee           = (float*)(wsb + WS_AEE);
  unsigned short* vpn  = (unsigned short*)(wsb + WS_VPN);
  int* eidx            = (int*)(wsb + WS_EIDX);
  unsigned short* corr = (unsigned short*)(wsb + WS_CORR);
  unsigned* uring      = (unsigned*)(wsb + WS_URING);
  unsigned long long* hx = (unsigned long long*)(wsb + WS_HX);
  unsigned* h0w        = (unsigned*)(wsb + WS_H0);
  unsigned* h1w        = (unsigned*)(wsb + WS_H1);
  unsigned short* h0u  = (unsigned short*)(wsb + WS_H0);
  unsigned short* h1u  = (unsigned short*)(wsb + WS_H1);

  (void)in_sizes; (void)n_in; (void)ws_size;

  hipMemsetAsync(d_ws, 0, 4096, stream);
  hipMemsetAsync(wsb + WS_HX, 0, 65536, stream);   // zero tags in hx
  hipMemsetAsync(d_out, 0, (size_t)out_size * 4, stream);

  k_prep_P<<<512, 256, 0, stream>>>(Wih0, ewW2, P);
  k_prep_aee_init<<<8, 256, 0, stream>>>(Wih0, ee, ewb1, ewb2, P, inith, aee, h0u, h1u);
  k_prep_vpn<<<LSEQ, 256, 0, stream>>>(Wih0, nemb, aee, vpn);
  k_prep_eidx<<<(NB * LSEQ) / 256, 256, 0, stream>>>(x_adj, eidx, counter);
  k_prep_corr<<<NB * LSEQ, 256, 0, stream>>>(x_adj, ewW1, ewb1, P, aee, eidx, corr);
  k_lstm<<<8, 512, 0, stream>>>(Whh0, Wih1, Whh1, vpn, eidx, corr, inith, initc,
                                flags, uring, hx, h0w, h1w);
  k_heads<<<254, 256, 0, stream>>>(h1u, x_adj, lgW1, lgb1, lgW2, lgb2,
                                   muW1, mub1, muW2, mub2, vaW1, vab1, vaW2, vab2,
                                   (float*)d_out);
}